// Round 7
// baseline (4710.221 us; speedup 1.0000x reference)
//
#include <hip/hip_runtime.h>

typedef unsigned int u32;
typedef unsigned long long u64;
typedef float f32x2 __attribute__((ext_vector_type(2)));

// ---------------- workspace layout (bytes) ----------------
#define WS_FEAT_A   0            // 2,097,152 f32 (8.39 MB)
#define WS_FEAT_B   8388608      // 2,097,152 f32
#define WS_XS0      16777216     // 49,152 f32
#define WS_XS1      16973824     // 49,152 f32
#define WS_FPS      21364736     // 16,384 i32
#define WS_KNN      21430272     // 524,288 i32
#define WS_PMAX     23527424     // 8*8*1024 f32
#define WS_PSUM     23789568     // 8*8*1024 f64
#define WS_ACC      24313856     // acc_xk(64 dbl) acc_fk(64 dbl) acc_g(48 dbl) = 176 dbl
#define WS_ACCI     24315392     // 48 dbl (init stats)
#define WS_PSTD     24315776     // 128 f32
#define WS_PINIT    24316288     // 2 f32

// ---- packed f32 (VOP3P) — exact IEEE mul/add on each half ----
__device__ __forceinline__ f32x2 pk_add(f32x2 a, f32x2 b) {
  f32x2 d;
  asm("v_pk_add_f32 %0, %1, %2" : "=v"(d) : "v"(a), "v"(b));
  return d;
}
__device__ __forceinline__ f32x2 pk_mul(f32x2 a, f32x2 b) {
  f32x2 d;
  asm("v_pk_mul_f32 %0, %1, %2" : "=v"(d) : "v"(a), "v"(b));
  return d;
}

// ---- DPP wave64 reductions (VALU) ----
__device__ __forceinline__ u32 dpp_umin_l63(u32 v) {
  u32 t;
  t = (u32)__builtin_amdgcn_update_dpp(-1, (int)v, 0x111, 0xf, 0xf, false); v = t < v ? t : v;
  t = (u32)__builtin_amdgcn_update_dpp(-1, (int)v, 0x112, 0xf, 0xf, false); v = t < v ? t : v;
  t = (u32)__builtin_amdgcn_update_dpp(-1, (int)v, 0x114, 0xf, 0xf, false); v = t < v ? t : v;
  t = (u32)__builtin_amdgcn_update_dpp(-1, (int)v, 0x118, 0xf, 0xf, false); v = t < v ? t : v;
  t = (u32)__builtin_amdgcn_update_dpp(-1, (int)v, 0x142, 0xf, 0xf, false); v = t < v ? t : v;
  t = (u32)__builtin_amdgcn_update_dpp(-1, (int)v, 0x143, 0xf, 0xf, false); v = t < v ? t : v;
  return (u32)__builtin_amdgcn_readlane((int)v, 63);
}

// u64 max across wave; bound_ctrl=true -> OOB lanes read 0 (identity: keys > 0).
__device__ __forceinline__ u64 dpp_umax64_l63(u64 v) {
#define DPP64_STEP(ctrl)                                                            \
  {                                                                                 \
    u32 lo = (u32)v, hi = (u32)(v >> 32);                                           \
    u32 tlo = (u32)__builtin_amdgcn_update_dpp(0, (int)lo, ctrl, 0xf, 0xf, true);   \
    u32 thi = (u32)__builtin_amdgcn_update_dpp(0, (int)hi, ctrl, 0xf, 0xf, true);   \
    u64 t = ((u64)thi << 32) | tlo;                                                 \
    v = t > v ? t : v;                                                              \
  }
  DPP64_STEP(0x111)
  DPP64_STEP(0x112)
  DPP64_STEP(0x114)
  DPP64_STEP(0x118)
  DPP64_STEP(0x142)
  DPP64_STEP(0x143)
#undef DPP64_STEP
  u32 rlo = (u32)__builtin_amdgcn_readlane((int)(u32)v, 63);
  u32 rhi = (u32)__builtin_amdgcn_readlane((int)(u32)(v >> 32), 63);
  return ((u64)rhi << 32) | rlo;
}

// ---- strict (non-contracted) float math matching numpy op order ----
__device__ __forceinline__ float sumsq3_nc(float x, float y, float z) {
#pragma clang fp contract(off)
  float d = x * x;
  d = d + y * y;
  d = d + z * z;
  return d;
}

__device__ __forceinline__ float knn_dist_nc(float qx, float qy, float qz, float qsq,
                                             float nx, float ny, float nz) {
#pragma clang fp contract(off)
  float dot = qx * nx;
  dot = dot + qy * ny;
  dot = dot + qz * nz;
  float nsq = nx * nx;
  nsq = nsq + ny * ny;
  nsq = nsq + nz * nz;
  float d = -2.0f * dot;
  d = d + qsq;
  d = d + nsq;
  return d;
}

// ================= FPS =================
// one block per batch; exact pointnet2 semantics (start at index 0).
// dist state held as u64 keys dkey[i] = dist_bits<<32 | (0xFFFFFFFF - gidx):
//   - update: dkey = min(dkey, cand) (same lo word -> pure dist compare; dists
//     >= 0 so bit order == float order)  [3 insts/pt + 4 pk insts/pt]
//   - argmax round winner = max key (max dist, tie -> min gidx = argmax
//     first-occurrence semantics), so NO separate argmax chain and NO tie path.
// Per-lane 4-level tree reduce carries {key, x, y, z} (leaf pair = the two
// halves of each f32x2; all indices static). Wave reduce = u64 DPP max;
// owner = ffs(ballot(key==max)) (unique by construction); coords readlane'd.
// NW>1: lane0 writes {key,x,y,z} slot; ONE barrier; all threads merge NW
// slots by key (coords travel with key -> no dependent point-cache read).
// No VMEM in the loop (indices buffered in LDS sidx, flushed at end).
template <int BLK, int P>
__global__ __launch_bounds__(BLK) void fps_kernel(const float* __restrict__ x,
                                                  int* __restrict__ out_idx, int S) {
  constexpr int NW = BLK / 64;
  constexpr int PH = P / 2;
  const int N = BLK * P;
  const int b = blockIdx.x;
  const float* xb = x + (size_t)b * N * 3;
  const int tid = threadIdx.x;
  const int lane = tid & 63;
  const int wid = tid >> 6;

  __shared__ alignas(16) u32 sred[2][NW < 2 ? 2 : NW][8];  // {keylo,keyhi,x,y,z,...}
  __shared__ int sidx[(NW > 1) ? (BLK * P / 2) : 1];

  f32x2 px2[PH], py2[PH], pz2[PH];
  u64 dkey[P];
  const u64 ik = ((u64)__float_as_uint(1e10f)) << 32;
#pragma unroll
  for (int i = 0; i < P; ++i) {
    int idx = i * BLK + tid;
    px2[i >> 1][i & 1] = xb[idx * 3 + 0];
    py2[i >> 1][i & 1] = xb[idx * 3 + 1];
    pz2[i >> 1][i & 1] = xb[idx * 3 + 2];
    dkey[i] = ik | (u64)(0xFFFFFFFFu - (u32)idx);
  }

  if constexpr (NW == 1) {
    if (tid == 0) out_idx[b * S + 0] = 0;
  }
  float lx = xb[0], ly = xb[1], lz = xb[2];

#pragma unroll 1
  for (int it = 1; it < S; ++it) {
    const int p = it & 1;
    // --- packed dist update into u64 keys ---
    f32x2 vnx, vny, vnz;
    vnx[0] = vnx[1] = __uint_as_float(__float_as_uint(lx) ^ 0x80000000u);
    vny[0] = vny[1] = __uint_as_float(__float_as_uint(ly) ^ 0x80000000u);
    vnz[0] = vnz[1] = __uint_as_float(__float_as_uint(lz) ^ 0x80000000u);
#pragma unroll
    for (int j = 0; j < PH; ++j) {
      f32x2 dx = pk_add(px2[j], vnx);
      f32x2 dy = pk_add(py2[j], vny);
      f32x2 dz = pk_add(pz2[j], vnz);
      f32x2 m0 = pk_mul(dx, dx);
      f32x2 m1 = pk_mul(dy, dy);
      f32x2 m2 = pk_mul(dz, dz);
      f32x2 s = pk_add(pk_add(m0, m1), m2);
#pragma unroll
      for (int h = 0; h < 2; ++h) {
        int i = 2 * j + h;
        u64 cand = (((u64)__float_as_uint(s[h])) << 32) |
                   (u64)(0xFFFFFFFFu - (u32)(i * BLK + tid));
        dkey[i] = (cand < dkey[i]) ? cand : dkey[i];
      }
    }

    // --- per-lane tree reduce carrying coords (all static indices) ---
    u64 tk[PH];
    float tx[PH], ty[PH], tz[PH];
#pragma unroll
    for (int j = 0; j < PH; ++j) {
      bool g = dkey[2 * j + 1] > dkey[2 * j];
      tk[j] = g ? dkey[2 * j + 1] : dkey[2 * j];
      tx[j] = g ? px2[j][1] : px2[j][0];
      ty[j] = g ? py2[j][1] : py2[j][0];
      tz[j] = g ? pz2[j][1] : pz2[j][0];
    }
#pragma unroll
    for (int w = PH / 2; w >= 1; w >>= 1) {
#pragma unroll
      for (int j = 0; j < w; ++j) {
        bool g = tk[j + w] > tk[j];
        tk[j] = g ? tk[j + w] : tk[j];
        tx[j] = g ? tx[j + w] : tx[j];
        ty[j] = g ? ty[j + w] : ty[j];
        tz[j] = g ? tz[j + w] : tz[j];
      }
    }

    // --- wave reduce: u64 DPP max; unique owner; coords via readlane ---
    u64 wk = dpp_umax64_l63(tk[0]);
    u64 cm = __ballot(tk[0] == wk);
    int owner = (int)__ffsll((long long)cm) - 1;
    float wx = __uint_as_float((u32)__builtin_amdgcn_readlane((int)__float_as_uint(tx[0]), owner));
    float wy = __uint_as_float((u32)__builtin_amdgcn_readlane((int)__float_as_uint(ty[0]), owner));
    float wz = __uint_as_float((u32)__builtin_amdgcn_readlane((int)__float_as_uint(tz[0]), owner));

    if constexpr (NW > 1) {
      if (lane == 0) {
        uint4 A;
        A.x = (u32)wk;
        A.y = (u32)(wk >> 32);
        A.z = __float_as_uint(wx);
        A.w = __float_as_uint(wy);
        *(uint4*)&sred[p][wid][0] = A;
        sred[p][wid][4] = __float_as_uint(wz);
      }
      __syncthreads();
      uint4 A = *(const uint4*)&sred[p][0][0];
      u32 az = sred[p][0][4];
#pragma unroll
      for (int w = 1; w < NW; ++w) {
        uint4 B = *(const uint4*)&sred[p][w][0];
        u32 bz = sred[p][w][4];
        u64 ka = ((u64)A.y << 32) | A.x;
        u64 kb = ((u64)B.y << 32) | B.x;
        bool g = kb > ka;
        A.x = g ? B.x : A.x;
        A.y = g ? B.y : A.y;
        A.z = g ? B.z : A.z;
        A.w = g ? B.w : A.w;
        az = g ? bz : az;
      }
      if (tid == 0) sidx[it] = (int)(0xFFFFFFFFu - A.x);
      lx = __uint_as_float(A.z);
      ly = __uint_as_float(A.w);
      lz = __uint_as_float(az);
    } else {
      if (lane == 0) out_idx[b * S + it] = (int)(0xFFFFFFFFu - (u32)wk);
      lx = wx;
      ly = wy;
      lz = wz;
    }
  }

  if constexpr (NW > 1) {
    __syncthreads();
    for (int i = tid; i < S; i += BLK) out_idx[b * S + i] = (i == 0) ? 0 : sidx[i];
  }
}

// ================= gather (xs only; fs is read through fidx downstream) =====
__global__ __launch_bounds__(256) void gather_xs_kernel(const float* __restrict__ x,
                                                        const int* __restrict__ fidx,
                                                        float* __restrict__ xs, int S, int N) {
  int t = blockIdx.x * 256 + threadIdx.x;
  if (t >= 8 * S * 3) return;
  int c = t % 3;
  int q = t / 3;
  int b = q / S;
  xs[t] = x[((size_t)b * N + fidx[q]) * 3 + c];
}

// ================= kNN (wave per query; DPP-min round reduce, exact order) ==
template <int P>  // N = 64*P candidates
__global__ __launch_bounds__(256) void knn_kernel(const float* __restrict__ x,
                                                  const float* __restrict__ xs,
                                                  int* __restrict__ knn, int S) {
  int wave = threadIdx.x >> 6, lane = threadIdx.x & 63;
  int q = blockIdx.x * 4 + wave;
  int b = q / S;
  const int N = 64 * P;
  const float* xb = x + (size_t)b * N * 3;
  float qx = xs[(size_t)q * 3 + 0];
  float qy = xs[(size_t)q * 3 + 1];
  float qz = xs[(size_t)q * 3 + 2];
  float qsq = sumsq3_nc(qx, qy, qz);

  u64 key[P];
#pragma unroll
  for (int i = 0; i < P; ++i) {
    int idx = i * 64 + lane;
    float nx = xb[idx * 3 + 0], ny = xb[idx * 3 + 1], nz = xb[idx * 3 + 2];
    float d = knn_dist_nc(qx, qy, qz, qsq, nx, ny, nz);
    u32 u = __float_as_uint(d);
    u32 msk = ((u32)(((int)u) >> 31)) | 0x80000000u;  // sortable float mapping
    u ^= msk;
    key[i] = ((u64)u << 32) | (u64)(u32)idx;
  }

  u64 prev = 0;
  u32 myv = 0;
#pragma unroll 1
  for (int r = 0; r < 32; ++r) {
    u64 best = ~0ull;
#pragma unroll
    for (int i = 0; i < P; ++i) {
      u64 k = key[i];
      u64 cand = (k > prev) ? k : ~0ull;
      best = (cand < best) ? cand : best;
    }
    // cand >= K (true next key) for all lanes => hi(cand) >= hi(K); exact.
    u32 hi = (u32)(best >> 32);
    u32 minb = dpp_umin_l63(hi);
    u64 cm = __ballot(hi == minb);
    u32 lo;
    if (__popcll(cm) == 1) {
      lo = (u32)__builtin_amdgcn_readlane((int)(u32)best, (int)__ffsll((long long)cm) - 1);
    } else {
      lo = dpp_umin_l63(hi == minb ? (u32)best : 0xFFFFFFFFu);
    }
    prev = ((u64)minb << 32) | lo;
    if (lane == r) myv = lo;
  }
  if (lane < 32) knn[(size_t)q * 32 + lane] = (int)myv;
}

// ================= per-k std stats (xk and fk) =================
template <int C>
__global__ __launch_bounds__(256) void stats1_kernel(const float* __restrict__ x,
                                                     const float* __restrict__ xs,
                                                     const float* __restrict__ feat,
                                                     const int* __restrict__ fidx,
                                                     const int* __restrict__ knn,
                                                     double* __restrict__ acc_xk,
                                                     double* __restrict__ acc_fk, int S, int N) {
  int k = threadIdx.x & 31;
  int qs = threadIdx.x >> 5;  // 0..7
  int qbase = blockIdx.x * 32;
  double sx = 0, sxx = 0, sf = 0, sff = 0;
  for (int jj = 0; jj < 4; ++jj) {
    int q = qbase + qs * 4 + jj;
    int b = q / S;
    int nbr = knn[(size_t)q * 32 + k];
    int fq = fidx[q];
    const float* xr = x + ((size_t)b * N + nbr) * 3;
    const float* xq = xs + (size_t)q * 3;
#pragma unroll
    for (int c = 0; c < 3; ++c) {
      float d = xr[c] - xq[c];
      sx += (double)d;
      sxx += (double)d * (double)d;
    }
    const float4* fr = (const float4*)(feat + ((size_t)b * N + nbr) * C);
    const float4* fqv = (const float4*)(feat + ((size_t)b * N + fq) * C);
    for (int c = 0; c < C / 4; ++c) {
      float4 a = fr[c], bb = fqv[c];
      float d0 = a.x - bb.x, d1 = a.y - bb.y, d2 = a.z - bb.z, d3 = a.w - bb.w;
      sf += (double)d0 + (double)d1 + (double)d2 + (double)d3;
      sff += (double)d0 * d0 + (double)d1 * d1 + (double)d2 * d2 + (double)d3 * d3;
    }
  }
  __shared__ double red[256];
  double vals[4] = {sx, sxx, sf, sff};
  double rr[4] = {0, 0, 0, 0};
#pragma unroll
  for (int p = 0; p < 4; ++p) {
    red[threadIdx.x] = vals[p];
    __syncthreads();
    if (threadIdx.x < 32) {
      double r = 0;
#pragma unroll
      for (int t = 0; t < 8; ++t) r += red[k + t * 32];
      rr[p] = r;
    }
    __syncthreads();
  }
  if (threadIdx.x < 32) {
    atomicAdd(&acc_xk[k * 2 + 0], rr[0]);
    atomicAdd(&acc_xk[k * 2 + 1], rr[1]);
    atomicAdd(&acc_fk[k * 2 + 0], rr[2]);
    atomicAdd(&acc_fk[k * 2 + 1], rr[3]);
  }
}

__global__ void finish_std(const double* __restrict__ acc_xk, const double* __restrict__ acc_fk,
                           float* __restrict__ pstd, int n1, int n2) {
  int k = threadIdx.x;
  if (k < 32) {
    double s = acc_xk[k * 2], ss = acc_xk[k * 2 + 1];
    double var = (ss - s * s / (double)n1) / (double)(n1 - 1);
    float st = (float)sqrt(var > 0.0 ? var : 0.0);
    st = fmaxf(st, 1e-5f);
    pstd[k] = 1.0f / st;
    s = acc_fk[k * 2];
    ss = acc_fk[k * 2 + 1];
    var = (ss - s * s / (double)n2) / (double)(n2 - 1);
    st = (float)sqrt(var > 0.0 ? var : 0.0);
    st = fmaxf(st, 1e-5f);
    pstd[32 + k] = 1.0f / st;
  }
}

// ================= gstd stats over normalized xk =================
__global__ __launch_bounds__(256) void stats2_kernel(const float* __restrict__ x,
                                                     const float* __restrict__ xs,
                                                     const int* __restrict__ knn,
                                                     const float* __restrict__ pstd,
                                                     double* __restrict__ acc_g, int S, int N) {
  int b = blockIdx.y;
  int total = S * 32;
  double a[3] = {0, 0, 0}, qq[3] = {0, 0, 0};
  for (int u = blockIdx.x * 256 + threadIdx.x; u < total; u += 32 * 256) {
    int s = u >> 5, k = u & 31;
    int nbr = knn[((size_t)b * S + s) * 32 + k];
    float is = pstd[k];
#pragma unroll
    for (int c = 0; c < 3; ++c) {
      float v = (x[((size_t)b * N + nbr) * 3 + c] - xs[((size_t)b * S + s) * 3 + c]) * is;
      a[c] += (double)v;
      qq[c] += (double)v * (double)v;
    }
  }
  __shared__ double red[256];
#pragma unroll
  for (int c = 0; c < 3; ++c) {
    red[threadIdx.x] = a[c];
    __syncthreads();
    for (int off = 128; off > 0; off >>= 1) {
      if (threadIdx.x < off) red[threadIdx.x] += red[threadIdx.x + off];
      __syncthreads();
    }
    if (threadIdx.x == 0) atomicAdd(&acc_g[(b * 3 + c) * 2], red[0]);
    __syncthreads();
    red[threadIdx.x] = qq[c];
    __syncthreads();
    for (int off = 128; off > 0; off >>= 1) {
      if (threadIdx.x < off) red[threadIdx.x] += red[threadIdx.x + off];
      __syncthreads();
    }
    if (threadIdx.x == 0) atomicAdd(&acc_g[(b * 3 + c) * 2 + 1], red[0]);
    __syncthreads();
  }
}

// gstd (24 slots of n samples each) -> params {inv(asig+eps), blend};
// then zeroes the stage accumulators (176 dbl) for the NEXT stage's atomics.
__global__ void finish_gstd(const double* __restrict__ acc, float* __restrict__ params, int n,
                            double* __restrict__ accz) {
  if (threadIdx.x == 0) {
    double g = 0;
    for (int i = 0; i < 24; ++i) {
      double s = acc[i * 2], ss = acc[i * 2 + 1];
      double var = (ss - s * s / (double)n) / (double)(n - 1);
      g += sqrt(var > 0.0 ? var : 0.0);
    }
    float gstd = (float)(g / 24.0);
    float asig = 0.26f * (1.0f + gstd);
    params[0] = 1.0f / (asig + 1e-6f);
    params[1] = 1.0f / (1.0f + expf(-(gstd - 0.1f) * 10.0f));
  }
  __syncthreads();
  for (int i = threadIdx.x; i < 176; i += 64) accz[i] = 0.0;
}

// ================= init stats + init embed =================
__global__ __launch_bounds__(256) void init_stats(const float* __restrict__ xyz,
                                                  double* __restrict__ acc) {
  int bc = blockIdx.x;
  int b = bc / 3, c = bc - b * 3;
  double s = 0, ss = 0;
  for (int n = threadIdx.x; n < 4096; n += 256) {
    float v = xyz[((size_t)b * 4096 + n) * 3 + c];
    s += (double)v;
    ss += (double)v * (double)v;
  }
  __shared__ double r1[256], r2[256];
  r1[threadIdx.x] = s;
  r2[threadIdx.x] = ss;
  __syncthreads();
  for (int off = 128; off > 0; off >>= 1) {
    if (threadIdx.x < off) {
      r1[threadIdx.x] += r1[threadIdx.x + off];
      r2[threadIdx.x] += r2[threadIdx.x + off];
    }
    __syncthreads();
  }
  if (threadIdx.x == 0) {
    acc[bc * 2] = r1[0];
    acc[bc * 2 + 1] = r2[0];
  }
}

__global__ __launch_bounds__(256) void init_embed(const float* __restrict__ xyz,
                                                  const float* __restrict__ params,
                                                  float* __restrict__ feat) {
  int t = blockIdx.x * 256 + threadIdx.x;  // over 8*4096*64
  int j = t & 63;
  int n = (t >> 6) & 4095;
  int b = t >> 18;
  float inv_ae = params[0], blend = params[1];
  int idx = (int)((double)j * 65.0 / 63.0);
  int c = idx / 22, f = idx - c * 22;
  float fv = (float)(-1.0 + 2.0 * (double)(f + 1) / 23.0);
  float v = xyz[((size_t)b * 4096 + n) * 3 + c];
  float z = (v - fv) * inv_ae;
  float e = __expf(-0.5f * z * z);
  float co = __cosf(z);
  feat[t] = blend * e + (1.0f - blend) * co;
}

// ================= fused embed + gate + K-reduce + gelu =================
template <int C, int TWOC, int BLK, int FD>
__global__ __launch_bounds__(BLK) void fused_kernel(const float* __restrict__ x,
                                                    const float* __restrict__ xs,
                                                    const float* __restrict__ feat_in,
                                                    const int* __restrict__ fidx,
                                                    const int* __restrict__ knn,
                                                    const float* __restrict__ pstd,
                                                    float* __restrict__ feat_out, int S, int N) {
  constexpr int JPT = TWOC / BLK;
  int q = blockIdx.x;
  int b = q / S;
  int tid = threadIdx.x;
  float inv_ae = pstd[64];
  float blend = pstd[65];
  float omb = 1.0f - blend;
  float c0 = xs[(size_t)q * 3 + 0];
  float c1 = xs[(size_t)q * 3 + 1];
  float c2 = xs[(size_t)q * 3 + 2];
  const float* fsrow = feat_in + ((size_t)b * N + fidx[q]) * C;

  int cj[JPT];
  float fvj[JPT], fj[JPT], sum[JPT], mx[JPT];
#pragma unroll
  for (int i = 0; i < JPT; ++i) {
    int j = tid + i * BLK;
    int idx = (int)((double)j * (double)(3 * FD - 1) / (double)(TWOC - 1));
    int c = idx / FD, f = idx - c * FD;
    cj[i] = c;
    fvj[i] = (float)(-1.0 + 2.0 * (double)(f + 1) / (double)(FD + 1));
    fj[i] = fsrow[j < C ? j : j - C];
    sum[i] = 0.0f;
    mx[i] = -3.4e38f;
  }

  const int* krow = knn + (size_t)q * 32;
#pragma unroll 1
  for (int k = 0; k < 32; ++k) {
    int nbr = krow[k];
    float isx = pstd[k], isf = pstd[32 + k];
    const float* xr = x + ((size_t)b * N + nbr) * 3;
    float xk0 = (xr[0] - c0) * isx;
    float xk1 = (xr[1] - c1) * isx;
    float xk2 = (xr[2] - c2) * isx;
    const float* fr = feat_in + ((size_t)b * N + nbr) * C;
#pragma unroll
    for (int i = 0; i < JPT; ++i) {
      int j = tid + i * BLK;
      float cat;
      if (j < C)
        cat = (fr[j] - fj[i]) * isf;
      else
        cat = fj[i];
      float xc = (cj[i] == 0) ? xk0 : ((cj[i] == 1) ? xk1 : xk2);
      float z = (xc - fvj[i]) * inv_ae;
      float comb = blend * __expf(-0.5f * z * z) + omb * __cosf(z);
      float fw = (cat + comb) * comb;
      sum[i] += fw;
      mx[i] = fmaxf(mx[i], fw);
    }
  }
#pragma unroll
  for (int i = 0; i < JPT; ++i) {
    float val = sum[i] * 0.03125f + mx[i];
    float g = 0.5f * val * (1.0f + erff(val * 0.7071067811865476f));
    feat_out[(size_t)q * TWOC + tid + i * BLK] = g;
  }
}

// ================= stage result reduce (max & mean over S) =================
template <int TWOC, int BLK>
__global__ __launch_bounds__(BLK) void result_partial(const float* __restrict__ feat,
                                                      float* __restrict__ pmax,
                                                      double* __restrict__ psum, int S) {
  int j = blockIdx.x * BLK + threadIdx.x;
  int ch = blockIdx.y, b = blockIdx.z;
  int rows = S >> 3;
  int s0 = ch * rows;
  float m = -3.4e38f;
  double sd = 0.0;
  for (int s = 0; s < rows; ++s) {
    float v = feat[((size_t)(b * S + s0 + s)) * TWOC + j];
    m = fmaxf(m, v);
    sd += (double)v;
  }
  pmax[((size_t)ch * 8 + b) * TWOC + j] = m;
  psum[((size_t)ch * 8 + b) * TWOC + j] = sd;
}

__global__ void result_final(const float* __restrict__ pmax, const double* __restrict__ psum,
                             float* __restrict__ out, int TWOC, int off, int S) {
  int t = blockIdx.x * 256 + threadIdx.x;
  if (t >= 8 * TWOC) return;
  int b = t / TWOC, j = t - b * TWOC;
  float m = -3.4e38f;
  double sd = 0.0;
  for (int ch = 0; ch < 8; ++ch) {
    m = fmaxf(m, pmax[((size_t)ch * 8 + b) * TWOC + j]);
    sd += psum[((size_t)ch * 8 + b) * TWOC + j];
  }
  out[(size_t)b * 3840 + off + j] = m;
  out[(size_t)b * 3840 + off + TWOC + j] = (float)(sd / (double)S);
}

// ================= stage driver =================
template <int N, int S, int C, int TWOC, int FD, int FBLK, int FP, int KP, int BLKF>
static void run_stage(const float* x, const float* feat_in, float* xs, float* feat_out,
                      int* fps, int* knnb, double* accz, float* pstd, float* pmax, double* psum,
                      float* out, int outoff, hipStream_t stream) {
  static_assert(FBLK * FP == N, "fps size");
  static_assert(64 * KP == N, "knn size");
  double* acc_xk = accz;
  double* acc_fk = accz + 64;
  double* acc_g = accz + 128;

  fps_kernel<FBLK, FP><<<8, FBLK, 0, stream>>>(x, fps, S);
  gather_xs_kernel<<<(8 * S * 3 + 255) / 256, 256, 0, stream>>>(x, fps, xs, S, N);
  knn_kernel<KP><<<(8 * S) / 4, 256, 0, stream>>>(x, xs, knnb, S);
  stats1_kernel<C><<<(8 * S) / 32, 256, 0, stream>>>(x, xs, feat_in, fps, knnb, acc_xk, acc_fk, S, N);
  finish_std<<<1, 64, 0, stream>>>(acc_xk, acc_fk, pstd, 8 * S * 3, 8 * S * C);
  stats2_kernel<<<dim3(32, 8), 256, 0, stream>>>(x, xs, knnb, pstd, acc_g, S, N);
  finish_gstd<<<1, 64, 0, stream>>>(acc_g, pstd + 64, S * 32, accz);
  fused_kernel<C, TWOC, BLKF, FD><<<8 * S, BLKF, 0, stream>>>(x, xs, feat_in, fps, knnb, pstd,
                                                              feat_out, S, N);
  constexpr int RBLK = (TWOC < 256) ? TWOC : 256;
  result_partial<TWOC, RBLK><<<dim3(TWOC / RBLK, 8, 8), RBLK, 0, stream>>>(feat_out, pmax, psum, S);
  result_final<<<(8 * TWOC + 255) / 256, 256, 0, stream>>>(pmax, psum, out, TWOC, outoff, S);
}

extern "C" void kernel_launch(void* const* d_in, const int* in_sizes, int n_in, void* d_out,
                              int out_size, void* d_ws, size_t ws_size, hipStream_t stream) {
  (void)in_sizes;
  (void)n_in;
  (void)out_size;
  (void)ws_size;
  const float* xyz = (const float*)d_in[0];
  float* out = (float*)d_out;
  char* w = (char*)d_ws;

  float* featA = (float*)(w + WS_FEAT_A);
  float* featB = (float*)(w + WS_FEAT_B);
  float* xs0 = (float*)(w + WS_XS0);
  float* xs1 = (float*)(w + WS_XS1);
  int* fps = (int*)(w + WS_FPS);
  int* knnb = (int*)(w + WS_KNN);
  float* pmax = (float*)(w + WS_PMAX);
  double* psum = (double*)(w + WS_PSUM);
  double* accz = (double*)(w + WS_ACC);
  double* acci = (double*)(w + WS_ACCI);
  float* pstd = (float*)(w + WS_PSTD);
  float* pinit = (float*)(w + WS_PINIT);

  // initial adaptive embed of xyz -> feat [8,4096,64]; finish_gstd also
  // zeroes the per-stage accumulators (covers first launch + graph replay).
  init_stats<<<24, 256, 0, stream>>>(xyz, acci);
  finish_gstd<<<1, 64, 0, stream>>>(acci, pinit, 4096, accz);
  init_embed<<<(8 * 4096 * 64) / 256, 256, 0, stream>>>(xyz, pinit, featA);

  // 4 stages
  run_stage<4096, 2048, 64, 128, 43, 256, 16, 64, 128>(xyz, featA, xs0, featB, fps, knnb,
                                                       accz, pstd, pmax, psum, out, 0, stream);
  run_stage<2048, 1024, 128, 256, 86, 256, 8, 32, 256>(xs0, featB, xs1, featA, fps, knnb,
                                                       accz, pstd, pmax, psum, out, 256, stream);
  run_stage<1024, 512, 256, 512, 171, 64, 16, 16, 256>(xs1, featA, xs0, featB, fps, knnb,
                                                       accz, pstd, pmax, psum, out, 768, stream);
  run_stage<512, 256, 512, 1024, 342, 64, 8, 8, 256>(xs0, featB, xs1, featA, fps, knnb,
                                                     accz, pstd, pmax, psum, out, 1792, stream);
}

// Round 8
// 3535.691 us; speedup vs baseline: 1.3322x; 1.3322x over previous
//
#include <hip/hip_runtime.h>

typedef unsigned int u32;
typedef unsigned long long u64;
typedef float f32x2 __attribute__((ext_vector_type(2)));

// ---------------- workspace layout (bytes) ----------------
#define WS_FEAT_A   0            // 2,097,152 f32 (8.39 MB)
#define WS_FEAT_B   8388608      // 2,097,152 f32
#define WS_XS0      16777216     // 49,152 f32
#define WS_XS1      16973824     // 49,152 f32
#define WS_FPS      21364736     // 16,384 i32
#define WS_KNN      21430272     // 524,288 i32
#define WS_PMAX     23527424     // 8*8*1024 f32
#define WS_PSUM     23789568     // 8*8*1024 f64
#define WS_ACC      24313856     // acc_xk(64 dbl) acc_fk(64 dbl) acc_g(48 dbl) = 176 dbl
#define WS_ACCI     24315392     // 48 dbl (init stats)
#define WS_PINIT    24316288     // 2 f32

// ---- packed f32 (VOP3P) — exact IEEE mul/add on each half ----
__device__ __forceinline__ f32x2 pk_add(f32x2 a, f32x2 b) {
  f32x2 d;
  asm("v_pk_add_f32 %0, %1, %2" : "=v"(d) : "v"(a), "v"(b));
  return d;
}
__device__ __forceinline__ f32x2 pk_mul(f32x2 a, f32x2 b) {
  f32x2 d;
  asm("v_pk_mul_f32 %0, %1, %2" : "=v"(d) : "v"(a), "v"(b));
  return d;
}

// ---- DPP wave64 reductions (VALU) ----
__device__ __forceinline__ u32 dpp_umax_l63(u32 v) {
  u32 t;
  t = (u32)__builtin_amdgcn_update_dpp(0, (int)v, 0x111, 0xf, 0xf, true); v = t > v ? t : v;
  t = (u32)__builtin_amdgcn_update_dpp(0, (int)v, 0x112, 0xf, 0xf, true); v = t > v ? t : v;
  t = (u32)__builtin_amdgcn_update_dpp(0, (int)v, 0x114, 0xf, 0xf, true); v = t > v ? t : v;
  t = (u32)__builtin_amdgcn_update_dpp(0, (int)v, 0x118, 0xf, 0xf, true); v = t > v ? t : v;
  t = (u32)__builtin_amdgcn_update_dpp(0, (int)v, 0x142, 0xf, 0xf, true); v = t > v ? t : v;
  t = (u32)__builtin_amdgcn_update_dpp(0, (int)v, 0x143, 0xf, 0xf, true); v = t > v ? t : v;
  return (u32)__builtin_amdgcn_readlane((int)v, 63);
}

__device__ __forceinline__ u32 dpp_umin_l63(u32 v) {
  u32 t;
  t = (u32)__builtin_amdgcn_update_dpp(-1, (int)v, 0x111, 0xf, 0xf, false); v = t < v ? t : v;
  t = (u32)__builtin_amdgcn_update_dpp(-1, (int)v, 0x112, 0xf, 0xf, false); v = t < v ? t : v;
  t = (u32)__builtin_amdgcn_update_dpp(-1, (int)v, 0x114, 0xf, 0xf, false); v = t < v ? t : v;
  t = (u32)__builtin_amdgcn_update_dpp(-1, (int)v, 0x118, 0xf, 0xf, false); v = t < v ? t : v;
  t = (u32)__builtin_amdgcn_update_dpp(-1, (int)v, 0x142, 0xf, 0xf, false); v = t < v ? t : v;
  t = (u32)__builtin_amdgcn_update_dpp(-1, (int)v, 0x143, 0xf, 0xf, false); v = t < v ? t : v;
  return (u32)__builtin_amdgcn_readlane((int)v, 63);
}

// ---- strict (non-contracted) float math matching numpy op order ----
__device__ __forceinline__ float sumsq3_nc(float x, float y, float z) {
#pragma clang fp contract(off)
  float d = x * x;
  d = d + y * y;
  d = d + z * z;
  return d;
}

__device__ __forceinline__ float knn_dist_nc(float qx, float qy, float qz, float qsq,
                                             float nx, float ny, float nz) {
#pragma clang fp contract(off)
  float dot = qx * nx;
  dot = dot + qy * ny;
  dot = dot + qz * nz;
  float nsq = nx * nx;
  nsq = nsq + ny * ny;
  nsq = nsq + nz * nz;
  float d = -2.0f * dot;
  d = d + qsq;
  d = d + nsq;
  return d;
}

// ================= FPS (round-6 structure, best measured) =================
// one block per batch; exact pointnet2 semantics (start at index 0).
// Per-round: packed-f32 dist update (v_pk_*, bit-exact) + local argmax on u32
// dist bits (strict > keeps smallest local idx) -> DPP u32-max -> ballot
// unique fast path (tie path exact, rare) -> [NW>1: lane0 ds_write_b64 wave
// key; ONE barrier; all threads read NW keys + u64-max merge] -> winner
// coords via ONE broadcast ds_read_b128 from LDS point cache.
// No VMEM in the NW>1 loop (indices buffered in LDS sidx, flushed at end;
// the flush also writes xs = selected coords, replacing gather_xs_kernel).
template <int BLK, int P>
__global__ __launch_bounds__(BLK) void fps_kernel(const float* __restrict__ x,
                                                  int* __restrict__ out_idx,
                                                  float* __restrict__ xs, int S) {
  constexpr int NW = BLK / 64;
  constexpr int PH = P / 2;
  const int N = BLK * P;
  const int b = blockIdx.x;
  const float* xb = x + (size_t)b * N * 3;
  const int tid = threadIdx.x;
  const int lane = tid & 63;
  const int wid = tid >> 6;

  __shared__ float4 spts[BLK * P];
  __shared__ alignas(16) u64 skey[2][NW < 2 ? 2 : NW];
  __shared__ int sidx[(NW > 1) ? (BLK * P / 2) : 1];

  f32x2 px2[PH], py2[PH], pz2[PH];
  float dist[P];
#pragma unroll
  for (int i = 0; i < P; ++i) {
    int idx = i * BLK + tid;
    float a = xb[idx * 3 + 0];
    float c = xb[idx * 3 + 1];
    float d = xb[idx * 3 + 2];
    px2[i >> 1][i & 1] = a;
    py2[i >> 1][i & 1] = c;
    pz2[i >> 1][i & 1] = d;
    dist[i] = 1e10f;
    spts[idx] = make_float4(a, c, d, 0.0f);
  }
  __syncthreads();

  float4 l4 = spts[0];
  float lx = l4.x, ly = l4.y, lz = l4.z;
  if constexpr (NW == 1) {
    if (tid == 0) {
      out_idx[b * S + 0] = 0;
      xs[(size_t)(b * S) * 3 + 0] = lx;
      xs[(size_t)(b * S) * 3 + 1] = ly;
      xs[(size_t)(b * S) * 3 + 2] = lz;
    }
  }

#pragma unroll 1
  for (int it = 1; it < S; ++it) {
    const int p = it & 1;
    // --- packed dist update + thread-local argmax ---
    f32x2 vnx, vny, vnz;
    vnx[0] = vnx[1] = __uint_as_float(__float_as_uint(lx) ^ 0x80000000u);
    vny[0] = vny[1] = __uint_as_float(__float_as_uint(ly) ^ 0x80000000u);
    vnz[0] = vnz[1] = __uint_as_float(__float_as_uint(lz) ^ 0x80000000u);
    u32 bd = 0;
    int bi = 0;
#pragma unroll
    for (int j = 0; j < PH; ++j) {
      f32x2 dx = pk_add(px2[j], vnx);
      f32x2 dy = pk_add(py2[j], vny);
      f32x2 dz = pk_add(pz2[j], vnz);
      f32x2 m0 = pk_mul(dx, dx);
      f32x2 m1 = pk_mul(dy, dy);
      f32x2 m2 = pk_mul(dz, dz);
      f32x2 s = pk_add(pk_add(m0, m1), m2);
#pragma unroll
      for (int h = 0; h < 2; ++h) {
        int i = 2 * j + h;
        float dm = fminf(dist[i], s[h]);
        dist[i] = dm;
        u32 db = __float_as_uint(dm);
        bool g = db > bd;  // strict > keeps smallest local idx (argmax first-occurrence)
        bd = g ? db : bd;
        bi = g ? i : bi;
      }
    }
    u32 bidx = (u32)(bi * BLK + tid);

    // --- wave argmax: DPP max of dist bits + exact tie handling ---
    u32 maxb = dpp_umax_l63(bd);
    u64 cm = __ballot(bd == maxb);
    u32 widx;
    if (__popcll(cm) == 1) {
      widx = (u32)__builtin_amdgcn_readlane((int)bidx, (int)__ffsll((long long)cm) - 1);
    } else {
      widx = 0xFFFFFFFFu - dpp_umax_l63((bd == maxb) ? (0xFFFFFFFFu - bidx) : 0u);
    }

    if constexpr (NW > 1) {
      if (lane == 0) skey[p][wid] = ((u64)maxb << 32) | (u64)(0xFFFFFFFFu - widx);
      __syncthreads();
      u64 best = skey[p][0];
#pragma unroll
      for (int w = 1; w < NW; ++w) {
        u64 kk = skey[p][w];
        best = (kk > best) ? kk : best;
      }
      widx = 0xFFFFFFFFu - (u32)best;
      if (tid == 0) sidx[it] = (int)widx;  // LDS buffer, flushed at end
    }

    // --- winner coords: single broadcast LDS read ---
    float4 c4 = spts[widx];
    lx = c4.x;
    ly = c4.y;
    lz = c4.z;

    if constexpr (NW == 1) {
      if (lane == 0) {
        out_idx[b * S + it] = (int)widx;  // no barrier in this path -> stores hidden
        xs[(size_t)(b * S + it) * 3 + 0] = lx;
        xs[(size_t)(b * S + it) * 3 + 1] = ly;
        xs[(size_t)(b * S + it) * 3 + 2] = lz;
      }
    }
  }

  if constexpr (NW > 1) {
    __syncthreads();
    for (int i = tid; i < S; i += BLK) {
      int idx = (i == 0) ? 0 : sidx[i];
      out_idx[b * S + i] = idx;
      float4 c4 = spts[idx];
      xs[(size_t)(b * S + i) * 3 + 0] = c4.x;
      xs[(size_t)(b * S + i) * 3 + 1] = c4.y;
      xs[(size_t)(b * S + i) * 3 + 2] = c4.z;
    }
  }
}

// ================= kNN (wave per query; DPP-min round reduce, exact order) ==
template <int P>  // N = 64*P candidates
__global__ __launch_bounds__(256) void knn_kernel(const float* __restrict__ x,
                                                  const float* __restrict__ xs,
                                                  int* __restrict__ knn, int S) {
  int wave = threadIdx.x >> 6, lane = threadIdx.x & 63;
  int q = blockIdx.x * 4 + wave;
  int b = q / S;
  const int N = 64 * P;
  const float* xb = x + (size_t)b * N * 3;
  float qx = xs[(size_t)q * 3 + 0];
  float qy = xs[(size_t)q * 3 + 1];
  float qz = xs[(size_t)q * 3 + 2];
  float qsq = sumsq3_nc(qx, qy, qz);

  u64 key[P];
#pragma unroll
  for (int i = 0; i < P; ++i) {
    int idx = i * 64 + lane;
    float nx = xb[idx * 3 + 0], ny = xb[idx * 3 + 1], nz = xb[idx * 3 + 2];
    float d = knn_dist_nc(qx, qy, qz, qsq, nx, ny, nz);
    u32 u = __float_as_uint(d);
    u32 msk = ((u32)(((int)u) >> 31)) | 0x80000000u;  // sortable float mapping
    u ^= msk;
    key[i] = ((u64)u << 32) | (u64)(u32)idx;
  }

  u64 prev = 0;
  u32 myv = 0;
#pragma unroll 1
  for (int r = 0; r < 32; ++r) {
    u64 best = ~0ull;
#pragma unroll
    for (int i = 0; i < P; ++i) {
      u64 k = key[i];
      u64 cand = (k > prev) ? k : ~0ull;
      best = (cand < best) ? cand : best;
    }
    // cand >= K (true next key) for all lanes => hi(cand) >= hi(K); exact.
    u32 hi = (u32)(best >> 32);
    u32 minb = dpp_umin_l63(hi);
    u64 cm = __ballot(hi == minb);
    u32 lo;
    if (__popcll(cm) == 1) {
      lo = (u32)__builtin_amdgcn_readlane((int)(u32)best, (int)__ffsll((long long)cm) - 1);
    } else {
      lo = dpp_umin_l63(hi == minb ? (u32)best : 0xFFFFFFFFu);
    }
    prev = ((u64)minb << 32) | lo;
    if (lane == r) myv = lo;
  }
  if (lane < 32) knn[(size_t)q * 32 + lane] = (int)myv;
}

// ================= per-k std stats (xk and fk) =================
template <int C>
__global__ __launch_bounds__(256) void stats1_kernel(const float* __restrict__ x,
                                                     const float* __restrict__ xs,
                                                     const float* __restrict__ feat,
                                                     const int* __restrict__ fidx,
                                                     const int* __restrict__ knn,
                                                     double* __restrict__ acc_xk,
                                                     double* __restrict__ acc_fk, int S, int N) {
  int k = threadIdx.x & 31;
  int qs = threadIdx.x >> 5;  // 0..7
  int qbase = blockIdx.x * 32;
  double sx = 0, sxx = 0, sf = 0, sff = 0;
  for (int jj = 0; jj < 4; ++jj) {
    int q = qbase + qs * 4 + jj;
    int b = q / S;
    int nbr = knn[(size_t)q * 32 + k];
    int fq = fidx[q];
    const float* xr = x + ((size_t)b * N + nbr) * 3;
    const float* xq = xs + (size_t)q * 3;
#pragma unroll
    for (int c = 0; c < 3; ++c) {
      float d = xr[c] - xq[c];
      sx += (double)d;
      sxx += (double)d * (double)d;
    }
    const float4* fr = (const float4*)(feat + ((size_t)b * N + nbr) * C);
    const float4* fqv = (const float4*)(feat + ((size_t)b * N + fq) * C);
    for (int c = 0; c < C / 4; ++c) {
      float4 a = fr[c], bb = fqv[c];
      float d0 = a.x - bb.x, d1 = a.y - bb.y, d2 = a.z - bb.z, d3 = a.w - bb.w;
      sf += (double)d0 + (double)d1 + (double)d2 + (double)d3;
      sff += (double)d0 * d0 + (double)d1 * d1 + (double)d2 * d2 + (double)d3 * d3;
    }
  }
  __shared__ double red[256];
  double vals[4] = {sx, sxx, sf, sff};
  double rr[4] = {0, 0, 0, 0};
#pragma unroll
  for (int p = 0; p < 4; ++p) {
    red[threadIdx.x] = vals[p];
    __syncthreads();
    if (threadIdx.x < 32) {
      double r = 0;
#pragma unroll
      for (int t = 0; t < 8; ++t) r += red[k + t * 32];
      rr[p] = r;
    }
    __syncthreads();
  }
  if (threadIdx.x < 32) {
    atomicAdd(&acc_xk[k * 2 + 0], rr[0]);
    atomicAdd(&acc_xk[k * 2 + 1], rr[1]);
    atomicAdd(&acc_fk[k * 2 + 0], rr[2]);
    atomicAdd(&acc_fk[k * 2 + 1], rr[3]);
  }
}

// ================= gstd stats over normalized xk =================
// self-computes the 32 xk inv-stds from acc_xk (replaces finish_std).
__global__ __launch_bounds__(256) void stats2_kernel(const float* __restrict__ x,
                                                     const float* __restrict__ xs,
                                                     const int* __restrict__ knn,
                                                     const double* __restrict__ acc_xk,
                                                     double* __restrict__ acc_g, int S, int N) {
  __shared__ float sisx[32];
  if (threadIdx.x < 32) {
    int k = threadIdx.x;
    int n1 = 8 * S * 3;
    double s = acc_xk[k * 2], ss = acc_xk[k * 2 + 1];
    double var = (ss - s * s / (double)n1) / (double)(n1 - 1);
    float st = (float)sqrt(var > 0.0 ? var : 0.0);
    st = fmaxf(st, 1e-5f);
    sisx[k] = 1.0f / st;
  }
  __syncthreads();

  int b = blockIdx.y;
  int total = S * 32;
  double a[3] = {0, 0, 0}, qq[3] = {0, 0, 0};
  for (int u = blockIdx.x * 256 + threadIdx.x; u < total; u += 32 * 256) {
    int s = u >> 5, k = u & 31;
    int nbr = knn[((size_t)b * S + s) * 32 + k];
    float is = sisx[k];
#pragma unroll
    for (int c = 0; c < 3; ++c) {
      float v = (x[((size_t)b * N + nbr) * 3 + c] - xs[((size_t)b * S + s) * 3 + c]) * is;
      a[c] += (double)v;
      qq[c] += (double)v * (double)v;
    }
  }
  __shared__ double red[256];
#pragma unroll
  for (int c = 0; c < 3; ++c) {
    red[threadIdx.x] = a[c];
    __syncthreads();
    for (int off = 128; off > 0; off >>= 1) {
      if (threadIdx.x < off) red[threadIdx.x] += red[threadIdx.x + off];
      __syncthreads();
    }
    if (threadIdx.x == 0) atomicAdd(&acc_g[(b * 3 + c) * 2], red[0]);
    __syncthreads();
    red[threadIdx.x] = qq[c];
    __syncthreads();
    for (int off = 128; off > 0; off >>= 1) {
      if (threadIdx.x < off) red[threadIdx.x] += red[threadIdx.x + off];
      __syncthreads();
    }
    if (threadIdx.x == 0) atomicAdd(&acc_g[(b * 3 + c) * 2 + 1], red[0]);
    __syncthreads();
  }
}

// init-only: gstd (24 slots of n samples each) -> params; zeroes accz.
__global__ void finish_gstd(const double* __restrict__ acc, float* __restrict__ params, int n,
                            double* __restrict__ accz) {
  if (threadIdx.x == 0) {
    double g = 0;
    for (int i = 0; i < 24; ++i) {
      double s = acc[i * 2], ss = acc[i * 2 + 1];
      double var = (ss - s * s / (double)n) / (double)(n - 1);
      g += sqrt(var > 0.0 ? var : 0.0);
    }
    float gstd = (float)(g / 24.0);
    float asig = 0.26f * (1.0f + gstd);
    params[0] = 1.0f / (asig + 1e-6f);
    params[1] = 1.0f / (1.0f + expf(-(gstd - 0.1f) * 10.0f));
  }
  __syncthreads();
  for (int i = threadIdx.x; i < 176; i += 64) accz[i] = 0.0;
}

// ================= init stats + init embed =================
__global__ __launch_bounds__(256) void init_stats(const float* __restrict__ xyz,
                                                  double* __restrict__ acc) {
  int bc = blockIdx.x;
  int b = bc / 3, c = bc - b * 3;
  double s = 0, ss = 0;
  for (int n = threadIdx.x; n < 4096; n += 256) {
    float v = xyz[((size_t)b * 4096 + n) * 3 + c];
    s += (double)v;
    ss += (double)v * (double)v;
  }
  __shared__ double r1[256], r2[256];
  r1[threadIdx.x] = s;
  r2[threadIdx.x] = ss;
  __syncthreads();
  for (int off = 128; off > 0; off >>= 1) {
    if (threadIdx.x < off) {
      r1[threadIdx.x] += r1[threadIdx.x + off];
      r2[threadIdx.x] += r2[threadIdx.x + off];
    }
    __syncthreads();
  }
  if (threadIdx.x == 0) {
    acc[bc * 2] = r1[0];
    acc[bc * 2 + 1] = r2[0];
  }
}

__global__ __launch_bounds__(256) void init_embed(const float* __restrict__ xyz,
                                                  const float* __restrict__ params,
                                                  float* __restrict__ feat) {
  int t = blockIdx.x * 256 + threadIdx.x;  // over 8*4096*64
  int j = t & 63;
  int n = (t >> 6) & 4095;
  int b = t >> 18;
  float inv_ae = params[0], blend = params[1];
  int idx = (int)((double)j * 65.0 / 63.0);
  int c = idx / 22, f = idx - c * 22;
  float fv = (float)(-1.0 + 2.0 * (double)(f + 1) / 23.0);
  float v = xyz[((size_t)b * 4096 + n) * 3 + c];
  float z = (v - fv) * inv_ae;
  float e = __expf(-0.5f * z * z);
  float co = __cosf(z);
  feat[t] = blend * e + (1.0f - blend) * co;
}

// ================= fused embed + gate + K-reduce + gelu =================
// self-computes all normalization params from the accumulators (replaces
// finish_std + finish_gstd outputs; verbatim math -> identical values).
template <int C, int TWOC, int BLK, int FD>
__global__ __launch_bounds__(BLK) void fused_kernel(const float* __restrict__ x,
                                                    const float* __restrict__ xs,
                                                    const float* __restrict__ feat_in,
                                                    const int* __restrict__ fidx,
                                                    const int* __restrict__ knn,
                                                    const double* __restrict__ acc,
                                                    float* __restrict__ feat_out, int S, int N) {
  constexpr int JPT = TWOC / BLK;
  int q = blockIdx.x;
  int b = q / S;
  int tid = threadIdx.x;

  __shared__ float spar[66];  // [0..31] isx, [32..63] isf, [64] inv_ae, [65] blend
  if (tid < 32) {
    int n1 = 8 * S * 3, n2 = 8 * S * C;
    double s = acc[tid * 2], ss = acc[tid * 2 + 1];
    double var = (ss - s * s / (double)n1) / (double)(n1 - 1);
    float st = (float)sqrt(var > 0.0 ? var : 0.0);
    st = fmaxf(st, 1e-5f);
    spar[tid] = 1.0f / st;
    s = acc[64 + tid * 2];
    ss = acc[64 + tid * 2 + 1];
    var = (ss - s * s / (double)n2) / (double)(n2 - 1);
    st = (float)sqrt(var > 0.0 ? var : 0.0);
    st = fmaxf(st, 1e-5f);
    spar[32 + tid] = 1.0f / st;
  } else if (tid == 32) {
    int ng = S * 32;
    double g = 0;
    for (int i = 0; i < 24; ++i) {
      double s = acc[128 + i * 2], ss = acc[128 + i * 2 + 1];
      double var = (ss - s * s / (double)ng) / (double)(ng - 1);
      g += sqrt(var > 0.0 ? var : 0.0);
    }
    float gstd = (float)(g / 24.0);
    float asig = 0.26f * (1.0f + gstd);
    spar[64] = 1.0f / (asig + 1e-6f);
    spar[65] = 1.0f / (1.0f + expf(-(gstd - 0.1f) * 10.0f));
  }
  __syncthreads();

  float inv_ae = spar[64];
  float blend = spar[65];
  float omb = 1.0f - blend;
  float c0 = xs[(size_t)q * 3 + 0];
  float c1 = xs[(size_t)q * 3 + 1];
  float c2 = xs[(size_t)q * 3 + 2];
  const float* fsrow = feat_in + ((size_t)b * N + fidx[q]) * C;

  int cj[JPT];
  float fvj[JPT], fj[JPT], sum[JPT], mx[JPT];
#pragma unroll
  for (int i = 0; i < JPT; ++i) {
    int j = tid + i * BLK;
    int idx = (int)((double)j * (double)(3 * FD - 1) / (double)(TWOC - 1));
    int c = idx / FD, f = idx - c * FD;
    cj[i] = c;
    fvj[i] = (float)(-1.0 + 2.0 * (double)(f + 1) / (double)(FD + 1));
    fj[i] = fsrow[j < C ? j : j - C];
    sum[i] = 0.0f;
    mx[i] = -3.4e38f;
  }

  const int* krow = knn + (size_t)q * 32;
#pragma unroll 1
  for (int k = 0; k < 32; ++k) {
    int nbr = krow[k];
    float isx = spar[k], isf = spar[32 + k];
    const float* xr = x + ((size_t)b * N + nbr) * 3;
    float xk0 = (xr[0] - c0) * isx;
    float xk1 = (xr[1] - c1) * isx;
    float xk2 = (xr[2] - c2) * isx;
    const float* fr = feat_in + ((size_t)b * N + nbr) * C;
#pragma unroll
    for (int i = 0; i < JPT; ++i) {
      int j = tid + i * BLK;
      float cat;
      if (j < C)
        cat = (fr[j] - fj[i]) * isf;
      else
        cat = fj[i];
      float xc = (cj[i] == 0) ? xk0 : ((cj[i] == 1) ? xk1 : xk2);
      float z = (xc - fvj[i]) * inv_ae;
      float comb = blend * __expf(-0.5f * z * z) + omb * __cosf(z);
      float fw = (cat + comb) * comb;
      sum[i] += fw;
      mx[i] = fmaxf(mx[i], fw);
    }
  }
#pragma unroll
  for (int i = 0; i < JPT; ++i) {
    float val = sum[i] * 0.03125f + mx[i];
    float g = 0.5f * val * (1.0f + erff(val * 0.7071067811865476f));
    feat_out[(size_t)q * TWOC + tid + i * BLK] = g;
  }
}

// ================= stage result reduce (max & mean over S) =================
template <int TWOC, int BLK>
__global__ __launch_bounds__(BLK) void result_partial(const float* __restrict__ feat,
                                                      float* __restrict__ pmax,
                                                      double* __restrict__ psum, int S) {
  int j = blockIdx.x * BLK + threadIdx.x;
  int ch = blockIdx.y, b = blockIdx.z;
  int rows = S >> 3;
  int s0 = ch * rows;
  float m = -3.4e38f;
  double sd = 0.0;
  for (int s = 0; s < rows; ++s) {
    float v = feat[((size_t)(b * S + s0 + s)) * TWOC + j];
    m = fmaxf(m, v);
    sd += (double)v;
  }
  pmax[((size_t)ch * 8 + b) * TWOC + j] = m;
  psum[((size_t)ch * 8 + b) * TWOC + j] = sd;
}

// also zeroes the stage accumulators for the NEXT stage (runs after fused
// has consumed them; stream-serial so safe).
__global__ void result_final(const float* __restrict__ pmax, const double* __restrict__ psum,
                             float* __restrict__ out, int TWOC, int off, int S,
                             double* __restrict__ accz) {
  if (blockIdx.x == 0 && threadIdx.x < 176) accz[threadIdx.x] = 0.0;
  int t = blockIdx.x * 256 + threadIdx.x;
  if (t >= 8 * TWOC) return;
  int b = t / TWOC, j = t - b * TWOC;
  float m = -3.4e38f;
  double sd = 0.0;
  for (int ch = 0; ch < 8; ++ch) {
    m = fmaxf(m, pmax[((size_t)ch * 8 + b) * TWOC + j]);
    sd += psum[((size_t)ch * 8 + b) * TWOC + j];
  }
  out[(size_t)b * 3840 + off + j] = m;
  out[(size_t)b * 3840 + off + TWOC + j] = (float)(sd / (double)S);
}

// ================= stage driver =================
template <int N, int S, int C, int TWOC, int FD, int FBLK, int FP, int KP, int BLKF>
static void run_stage(const float* x, const float* feat_in, float* xs, float* feat_out,
                      int* fps, int* knnb, double* accz, float* pmax, double* psum,
                      float* out, int outoff, hipStream_t stream) {
  static_assert(FBLK * FP == N, "fps size");
  static_assert(64 * KP == N, "knn size");
  double* acc_xk = accz;
  double* acc_fk = accz + 64;
  double* acc_g = accz + 128;

  fps_kernel<FBLK, FP><<<8, FBLK, 0, stream>>>(x, fps, xs, S);
  knn_kernel<KP><<<(8 * S) / 4, 256, 0, stream>>>(x, xs, knnb, S);
  stats1_kernel<C><<<(8 * S) / 32, 256, 0, stream>>>(x, xs, feat_in, fps, knnb, acc_xk, acc_fk, S, N);
  stats2_kernel<<<dim3(32, 8), 256, 0, stream>>>(x, xs, knnb, acc_xk, acc_g, S, N);
  fused_kernel<C, TWOC, BLKF, FD><<<8 * S, BLKF, 0, stream>>>(x, xs, feat_in, fps, knnb, accz,
                                                              feat_out, S, N);
  constexpr int RBLK = (TWOC < 256) ? TWOC : 256;
  result_partial<TWOC, RBLK><<<dim3(TWOC / RBLK, 8, 8), RBLK, 0, stream>>>(feat_out, pmax, psum, S);
  result_final<<<(8 * TWOC + 255) / 256, 256, 0, stream>>>(pmax, psum, out, TWOC, outoff, S, accz);
}

extern "C" void kernel_launch(void* const* d_in, const int* in_sizes, int n_in, void* d_out,
                              int out_size, void* d_ws, size_t ws_size, hipStream_t stream) {
  (void)in_sizes;
  (void)n_in;
  (void)out_size;
  (void)ws_size;
  const float* xyz = (const float*)d_in[0];
  float* out = (float*)d_out;
  char* w = (char*)d_ws;

  float* featA = (float*)(w + WS_FEAT_A);
  float* featB = (float*)(w + WS_FEAT_B);
  float* xs0 = (float*)(w + WS_XS0);
  float* xs1 = (float*)(w + WS_XS1);
  int* fps = (int*)(w + WS_FPS);
  int* knnb = (int*)(w + WS_KNN);
  float* pmax = (float*)(w + WS_PMAX);
  double* psum = (double*)(w + WS_PSUM);
  double* accz = (double*)(w + WS_ACC);
  double* acci = (double*)(w + WS_ACCI);
  float* pinit = (float*)(w + WS_PINIT);

  // initial adaptive embed of xyz -> feat [8,4096,64]; finish_gstd also
  // zeroes the per-stage accumulators (covers first launch + graph replay).
  init_stats<<<24, 256, 0, stream>>>(xyz, acci);
  finish_gstd<<<1, 64, 0, stream>>>(acci, pinit, 4096, accz);
  init_embed<<<(8 * 4096 * 64) / 256, 256, 0, stream>>>(xyz, pinit, featA);

  // 4 stages
  run_stage<4096, 2048, 64, 128, 43, 256, 16, 64, 128>(xyz, featA, xs0, featB, fps, knnb,
                                                       accz, pmax, psum, out, 0, stream);
  run_stage<2048, 1024, 128, 256, 86, 64, 32, 32, 256>(xs0, featB, xs1, featA, fps, knnb,
                                                       accz, pmax, psum, out, 256, stream);
  run_stage<1024, 512, 256, 512, 171, 64, 16, 16, 256>(xs1, featA, xs0, featB, fps, knnb,
                                                       accz, pmax, psum, out, 768, stream);
  run_stage<512, 256, 512, 1024, 342, 64, 8, 8, 256>(xs0, featB, xs1, featA, fps, knnb,
                                                     accz, pmax, psum, out, 1792, stream);
}

// Round 10
// 2575.516 us; speedup vs baseline: 1.8288x; 1.3728x over previous
//
#include <hip/hip_runtime.h>

typedef unsigned int u32;
typedef unsigned long long u64;
typedef float f32x2 __attribute__((ext_vector_type(2)));

// ---------------- workspace layout (bytes, non-overlapping) ----------------
#define WS_FEAT_A   0            // 8,388,608 B (max feat buf: 8*4096*64 f32)
#define WS_FEAT_B   8388608      // 8,388,608 B
#define WS_XS0      16777216     // 8*2048*3 f32 = 196,608 B
#define WS_XS1      16973824     // 8*1024*3 f32 =  98,304 B
#define WS_XS2      17072128     // 8*512*3  f32 =  49,152 B
#define WS_XS3      17121280     // 8*256*3  f32 =  24,576 B
#define WS_FP0      17145856     // 8*2048 i32 = 65,536 B
#define WS_FP1      17211392     // 8*1024 i32 = 32,768 B
#define WS_FP2      17244160     // 8*512  i32 = 16,384 B
#define WS_FP3      17260544     // 8*256  i32 =  8,192 B
#define WS_ACC      17268736     // 1600 dbl = 12,800 B: accG[24][32][2] + acc_fk[64]
#define WS_ACCI     17281536     // 48 dbl = 384 B
#define WS_PSTD     17281920     // 66 f32 (padded to 512 B)
#define WS_PINIT    17282432     // 2 f32
#define WS_KNN      17282560     // 8*2048*32 i32 = 2,097,152 B
#define WS_PMAX     19379712     // 8*8*1024 f32 = 262,144 B
#define WS_PSUM     19641856     // 8*8*1024 f64 = 524,288 B  (ends 20,166,144)

// ---- packed f32 (VOP3P) — exact IEEE mul/add on each half ----
__device__ __forceinline__ f32x2 pk_add(f32x2 a, f32x2 b) {
  f32x2 d;
  asm("v_pk_add_f32 %0, %1, %2" : "=v"(d) : "v"(a), "v"(b));
  return d;
}
__device__ __forceinline__ f32x2 pk_mul(f32x2 a, f32x2 b) {
  f32x2 d;
  asm("v_pk_mul_f32 %0, %1, %2" : "=v"(d) : "v"(a), "v"(b));
  return d;
}

// ---- DPP wave64 reductions (VALU) ----
__device__ __forceinline__ u32 dpp_umax_l63(u32 v) {
  u32 t;
  t = (u32)__builtin_amdgcn_update_dpp(0, (int)v, 0x111, 0xf, 0xf, true); v = t > v ? t : v;
  t = (u32)__builtin_amdgcn_update_dpp(0, (int)v, 0x112, 0xf, 0xf, true); v = t > v ? t : v;
  t = (u32)__builtin_amdgcn_update_dpp(0, (int)v, 0x114, 0xf, 0xf, true); v = t > v ? t : v;
  t = (u32)__builtin_amdgcn_update_dpp(0, (int)v, 0x118, 0xf, 0xf, true); v = t > v ? t : v;
  t = (u32)__builtin_amdgcn_update_dpp(0, (int)v, 0x142, 0xf, 0xf, true); v = t > v ? t : v;
  t = (u32)__builtin_amdgcn_update_dpp(0, (int)v, 0x143, 0xf, 0xf, true); v = t > v ? t : v;
  return (u32)__builtin_amdgcn_readlane((int)v, 63);
}

__device__ __forceinline__ u32 dpp_umin_l63(u32 v) {
  u32 t;
  t = (u32)__builtin_amdgcn_update_dpp(-1, (int)v, 0x111, 0xf, 0xf, false); v = t < v ? t : v;
  t = (u32)__builtin_amdgcn_update_dpp(-1, (int)v, 0x112, 0xf, 0xf, false); v = t < v ? t : v;
  t = (u32)__builtin_amdgcn_update_dpp(-1, (int)v, 0x114, 0xf, 0xf, false); v = t < v ? t : v;
  t = (u32)__builtin_amdgcn_update_dpp(-1, (int)v, 0x118, 0xf, 0xf, false); v = t < v ? t : v;
  t = (u32)__builtin_amdgcn_update_dpp(-1, (int)v, 0x142, 0xf, 0xf, false); v = t < v ? t : v;
  t = (u32)__builtin_amdgcn_update_dpp(-1, (int)v, 0x143, 0xf, 0xf, false); v = t < v ? t : v;
  return (u32)__builtin_amdgcn_readlane((int)v, 63);
}

// ---- strict (non-contracted) float math matching numpy op order ----
__device__ __forceinline__ float sumsq3_nc(float x, float y, float z) {
#pragma clang fp contract(off)
  float d = x * x;
  d = d + y * y;
  d = d + z * z;
  return d;
}

__device__ __forceinline__ float knn_dist_nc(float qx, float qy, float qz, float qsq,
                                             float nx, float ny, float nz) {
#pragma clang fp contract(off)
  float dot = qx * nx;
  dot = dot + qy * ny;
  dot = dot + qz * nz;
  float nsq = nx * nx;
  nsq = nsq + ny * ny;
  nsq = nsq + nz * nz;
  float d = -2.0f * dot;
  d = d + qsq;
  d = d + nsq;
  return d;
}

// ================= FPS body (round-6 structure, best measured) =============
// exact pointnet2 semantics (start at index 0); writes out_idx AND xs coords.
template <int BLK, int P>
__device__ __forceinline__ void fps_body(const float* __restrict__ x,
                                         int* __restrict__ out_idx,
                                         float* __restrict__ xs, int S, int b) {
  constexpr int NW = BLK / 64;
  constexpr int PH = P / 2;
  const int N = BLK * P;
  const float* xb = x + (size_t)b * N * 3;
  const int tid = threadIdx.x;
  const int lane = tid & 63;
  const int wid = tid >> 6;

  __shared__ float4 spts[BLK * P];
  __shared__ alignas(16) u64 skey[2][NW < 2 ? 2 : NW];
  __shared__ int sidx[(NW > 1) ? (BLK * P / 2) : 1];

  f32x2 px2[PH], py2[PH], pz2[PH];
  float dist[P];
#pragma unroll
  for (int i = 0; i < P; ++i) {
    int idx = i * BLK + tid;
    float a = xb[idx * 3 + 0];
    float c = xb[idx * 3 + 1];
    float d = xb[idx * 3 + 2];
    px2[i >> 1][i & 1] = a;
    py2[i >> 1][i & 1] = c;
    pz2[i >> 1][i & 1] = d;
    dist[i] = 1e10f;
    spts[idx] = make_float4(a, c, d, 0.0f);
  }
  __syncthreads();

  float4 l4 = spts[0];
  float lx = l4.x, ly = l4.y, lz = l4.z;
  if constexpr (NW == 1) {
    if (tid == 0) {
      out_idx[b * S + 0] = 0;
      xs[(size_t)(b * S) * 3 + 0] = lx;
      xs[(size_t)(b * S) * 3 + 1] = ly;
      xs[(size_t)(b * S) * 3 + 2] = lz;
    }
  }

#pragma unroll 1
  for (int it = 1; it < S; ++it) {
    const int p = it & 1;
    f32x2 vnx, vny, vnz;
    vnx[0] = vnx[1] = __uint_as_float(__float_as_uint(lx) ^ 0x80000000u);
    vny[0] = vny[1] = __uint_as_float(__float_as_uint(ly) ^ 0x80000000u);
    vnz[0] = vnz[1] = __uint_as_float(__float_as_uint(lz) ^ 0x80000000u);
    u32 bd = 0;
    int bi = 0;
#pragma unroll
    for (int j = 0; j < PH; ++j) {
      f32x2 dx = pk_add(px2[j], vnx);
      f32x2 dy = pk_add(py2[j], vny);
      f32x2 dz = pk_add(pz2[j], vnz);
      f32x2 m0 = pk_mul(dx, dx);
      f32x2 m1 = pk_mul(dy, dy);
      f32x2 m2 = pk_mul(dz, dz);
      f32x2 s = pk_add(pk_add(m0, m1), m2);
#pragma unroll
      for (int h = 0; h < 2; ++h) {
        int i = 2 * j + h;
        float dm = fminf(dist[i], s[h]);
        dist[i] = dm;
        u32 db = __float_as_uint(dm);
        bool g = db > bd;  // strict > keeps smallest local idx (argmax first-occurrence)
        bd = g ? db : bd;
        bi = g ? i : bi;
      }
    }
    u32 bidx = (u32)(bi * BLK + tid);

    u32 maxb = dpp_umax_l63(bd);
    u64 cm = __ballot(bd == maxb);
    u32 widx;
    if (__popcll(cm) == 1) {
      widx = (u32)__builtin_amdgcn_readlane((int)bidx, (int)__ffsll((long long)cm) - 1);
    } else {
      widx = 0xFFFFFFFFu - dpp_umax_l63((bd == maxb) ? (0xFFFFFFFFu - bidx) : 0u);
    }

    if constexpr (NW > 1) {
      if (lane == 0) skey[p][wid] = ((u64)maxb << 32) | (u64)(0xFFFFFFFFu - widx);
      __syncthreads();
      u64 best = skey[p][0];
#pragma unroll
      for (int w = 1; w < NW; ++w) {
        u64 kk = skey[p][w];
        best = (kk > best) ? kk : best;
      }
      widx = 0xFFFFFFFFu - (u32)best;
      if (tid == 0) sidx[it] = (int)widx;
    }

    float4 c4 = spts[widx];
    lx = c4.x;
    ly = c4.y;
    lz = c4.z;

    if constexpr (NW == 1) {
      if (lane == 0) {
        out_idx[b * S + it] = (int)widx;
        xs[(size_t)(b * S + it) * 3 + 0] = lx;
        xs[(size_t)(b * S + it) * 3 + 1] = ly;
        xs[(size_t)(b * S + it) * 3 + 2] = lz;
      }
    }
  }

  if constexpr (NW > 1) {
    __syncthreads();
    for (int i = tid; i < S; i += BLK) {
      int idx = (i == 0) ? 0 : sidx[i];
      out_idx[b * S + i] = idx;
      float4 c4 = spts[idx];
      xs[(size_t)(b * S + i) * 3 + 0] = c4.x;
      xs[(size_t)(b * S + i) * 3 + 1] = c4.y;
      xs[(size_t)(b * S + i) * 3 + 2] = c4.z;
    }
  }
}

template <int BLK, int P>
__global__ __launch_bounds__(BLK) void fps_kernel(const float* __restrict__ x,
                                                  int* __restrict__ out_idx,
                                                  float* __restrict__ xs, int S) {
  fps_body<BLK, P>(x, out_idx, xs, S, blockIdx.x);
}

// ================= kNN body (wave per query; DPP-min rounds, exact) ========
template <int P>  // N = 64*P candidates
__device__ __forceinline__ void knn_body(const float* __restrict__ x,
                                         const float* __restrict__ xs,
                                         int* __restrict__ knn, int S, int q, int lane) {
  int b = q / S;
  const int N = 64 * P;
  const float* xb = x + (size_t)b * N * 3;
  float qx = xs[(size_t)q * 3 + 0];
  float qy = xs[(size_t)q * 3 + 1];
  float qz = xs[(size_t)q * 3 + 2];
  float qsq = sumsq3_nc(qx, qy, qz);

  u64 key[P];
#pragma unroll
  for (int i = 0; i < P; ++i) {
    int idx = i * 64 + lane;
    float nx = xb[idx * 3 + 0], ny = xb[idx * 3 + 1], nz = xb[idx * 3 + 2];
    float d = knn_dist_nc(qx, qy, qz, qsq, nx, ny, nz);
    u32 u = __float_as_uint(d);
    u32 msk = ((u32)(((int)u) >> 31)) | 0x80000000u;  // sortable float mapping
    u ^= msk;
    key[i] = ((u64)u << 32) | (u64)(u32)idx;
  }

  u64 prev = 0;
  u32 myv = 0;
#pragma unroll 1
  for (int r = 0; r < 32; ++r) {
    u64 best = ~0ull;
#pragma unroll
    for (int i = 0; i < P; ++i) {
      u64 k = key[i];
      u64 cand = (k > prev) ? k : ~0ull;
      best = (cand < best) ? cand : best;
    }
    u32 hi = (u32)(best >> 32);
    u32 minb = dpp_umin_l63(hi);
    u64 cm = __ballot(hi == minb);
    u32 lo;
    if (__popcll(cm) == 1) {
      lo = (u32)__builtin_amdgcn_readlane((int)(u32)best, (int)__ffsll((long long)cm) - 1);
    } else {
      lo = dpp_umin_l63(hi == minb ? (u32)best : 0xFFFFFFFFu);
    }
    prev = ((u64)minb << 32) | lo;
    if (lane == r) myv = lo;
  }
  if (lane < 32) knn[(size_t)q * 32 + lane] = (int)myv;
}

template <int P>
__global__ __launch_bounds__(256) void knn_kernel(const float* __restrict__ x,
                                                  const float* __restrict__ xs,
                                                  int* __restrict__ knn, int S) {
  knn_body<P>(x, xs, knn, S, blockIdx.x * 4 + (threadIdx.x >> 6), threadIdx.x & 63);
}

// ======= co-scheduled kernel: blocks 0..7 = fps of NEXT stage; rest = kNN ===
// Both consume only already-written buffers (xs_cur, x_cur); outputs disjoint.
template <int FBLK, int FP, int KP, int KWPB>
__global__ __launch_bounds__(FBLK) void co_fps_knn(const float* __restrict__ xf,
                                                   int* __restrict__ fps_out,
                                                   float* __restrict__ xs_out, int Sn,
                                                   const float* __restrict__ xk,
                                                   const float* __restrict__ xsq,
                                                   int* __restrict__ knn_out, int Sk) {
  if (blockIdx.x < 8) {
    fps_body<FBLK, FP>(xf, fps_out, xs_out, Sn, blockIdx.x);
  } else {
    int lane = threadIdx.x & 63;
    int q = (blockIdx.x - 8) * KWPB + (KWPB > 1 ? (int)(threadIdx.x >> 6) : 0);
    knn_body<KP>(xk, xsq, knn_out, Sk, q, lane);
  }
}

// ================= stats1: per-(b,c,k) raw sums + per-k feature sums ========
// accG layout: [(b*3+c)*32 + k] * 2 doubles; acc_fk at acc+1536.
template <int C>
__global__ __launch_bounds__(256) void stats1_kernel(const float* __restrict__ x,
                                                     const float* __restrict__ xs,
                                                     const float* __restrict__ feat,
                                                     const int* __restrict__ fidx,
                                                     const int* __restrict__ knn,
                                                     double* __restrict__ acc, int S, int N) {
  int k = threadIdx.x & 31;
  int qs = threadIdx.x >> 5;  // 0..7
  int qbase = blockIdx.x * 32;
  int b = qbase / S;  // uniform: 32 consecutive q's share b (S multiple of 32)
  double sx[3] = {0, 0, 0}, sxx[3] = {0, 0, 0}, sf = 0, sff = 0;
  for (int jj = 0; jj < 4; ++jj) {
    int q = qbase + qs * 4 + jj;
    int nbr = knn[(size_t)q * 32 + k];
    int fq = fidx[q];
    const float* xr = x + ((size_t)b * N + nbr) * 3;
    const float* xq = xs + (size_t)q * 3;
#pragma unroll
    for (int c = 0; c < 3; ++c) {
      float d = xr[c] - xq[c];
      sx[c] += (double)d;
      sxx[c] += (double)d * (double)d;
    }
    const float4* fr = (const float4*)(feat + ((size_t)b * N + nbr) * C);
    const float4* fqv = (const float4*)(feat + ((size_t)b * N + fq) * C);
    for (int c = 0; c < C / 4; ++c) {
      float4 a = fr[c], bb = fqv[c];
      float d0 = a.x - bb.x, d1 = a.y - bb.y, d2 = a.z - bb.z, d3 = a.w - bb.w;
      sf += (double)d0 + (double)d1 + (double)d2 + (double)d3;
      sff += (double)d0 * d0 + (double)d1 * d1 + (double)d2 * d2 + (double)d3 * d3;
    }
  }
  __shared__ double red[256];
  double vals[8] = {sx[0], sxx[0], sx[1], sxx[1], sx[2], sxx[2], sf, sff};
  double* accG = acc;
  double* acc_fk = acc + 1536;
#pragma unroll
  for (int p = 0; p < 8; ++p) {
    red[threadIdx.x] = vals[p];
    __syncthreads();
    if (threadIdx.x < 32) {
      double r = 0;
#pragma unroll
      for (int t = 0; t < 8; ++t) r += red[k + t * 32];
      if (p < 6) {
        int c = p >> 1;
        atomicAdd(&accG[((b * 3 + c) * 32 + k) * 2 + (p & 1)], r);
      } else {
        atomicAdd(&acc_fk[k * 2 + (p & 1)], r);
      }
    }
    __syncthreads();
  }
}

// ================= fin: per-stage params (once!), then zero acc =============
__global__ void fin_kernel(double* __restrict__ acc, float* __restrict__ pstd, int S, int C) {
  __shared__ float sisx[32];
  __shared__ double gslot[24];
  int tid = threadIdx.x;
  const double* accG = acc;
  const double* afk = acc + 1536;
  if (tid < 32) {
    double sd = 0, sdd = 0;
    for (int bc = 0; bc < 24; ++bc) {
      sd += accG[(bc * 32 + tid) * 2];
      sdd += accG[(bc * 32 + tid) * 2 + 1];
    }
    int n1 = 8 * S * 3;
    double var = (sdd - sd * sd / (double)n1) / (double)(n1 - 1);
    float st = fmaxf((float)sqrt(var > 0.0 ? var : 0.0), 1e-5f);
    sisx[tid] = 1.0f / st;
    pstd[tid] = sisx[tid];
    double s = afk[tid * 2], ss = afk[tid * 2 + 1];
    int n2 = 8 * S * C;
    var = (ss - s * s / (double)n2) / (double)(n2 - 1);
    st = fmaxf((float)sqrt(var > 0.0 ? var : 0.0), 1e-5f);
    pstd[32 + tid] = 1.0f / st;
  }
  __syncthreads();
  if (tid < 24) {
    // std over (s,k) of d*is_k per (b,c): separable via per-(b,c,k) raw sums.
    double A = 0, B = 0;
    for (int k = 0; k < 32; ++k) {
      double is = (double)sisx[k];
      A += is * accG[(tid * 32 + k) * 2];
      B += is * is * accG[(tid * 32 + k) * 2 + 1];
    }
    int ng = S * 32;
    double var = (B - A * A / (double)ng) / (double)(ng - 1);
    gslot[tid] = sqrt(var > 0.0 ? var : 0.0);
  }
  __syncthreads();
  if (tid == 0) {
    double g = 0;
    for (int i = 0; i < 24; ++i) g += gslot[i];
    float gstd = (float)(g / 24.0);
    float asig = 0.26f * (1.0f + gstd);
    pstd[64] = 1.0f / (asig + 1e-6f);
    pstd[65] = 1.0f / (1.0f + expf(-(gstd - 0.1f) * 10.0f));
  }
  __syncthreads();
  for (int i = tid; i < 1600; i += 64) acc[i] = 0.0;  // ready for next stage
}

// ================= init stats + init params + init embed ====================
__global__ __launch_bounds__(256) void init_stats(const float* __restrict__ xyz,
                                                  double* __restrict__ acc) {
  int bc = blockIdx.x;
  int b = bc / 3, c = bc - b * 3;
  double s = 0, ss = 0;
  for (int n = threadIdx.x; n < 4096; n += 256) {
    float v = xyz[((size_t)b * 4096 + n) * 3 + c];
    s += (double)v;
    ss += (double)v * (double)v;
  }
  __shared__ double r1[256], r2[256];
  r1[threadIdx.x] = s;
  r2[threadIdx.x] = ss;
  __syncthreads();
  for (int off = 128; off > 0; off >>= 1) {
    if (threadIdx.x < off) {
      r1[threadIdx.x] += r1[threadIdx.x + off];
      r2[threadIdx.x] += r2[threadIdx.x + off];
    }
    __syncthreads();
  }
  if (threadIdx.x == 0) {
    acc[bc * 2] = r1[0];
    acc[bc * 2 + 1] = r2[0];
  }
}

// init params from acci (24 slots, n=4096) + zero the 1600-dbl stage acc.
__global__ void fin_init(const double* __restrict__ acc, float* __restrict__ params,
                         double* __restrict__ accz) {
  if (threadIdx.x == 0) {
    double g = 0;
    for (int i = 0; i < 24; ++i) {
      double s = acc[i * 2], ss = acc[i * 2 + 1];
      double var = (ss - s * s / 4096.0) / 4095.0;
      g += sqrt(var > 0.0 ? var : 0.0);
    }
    float gstd = (float)(g / 24.0);
    float asig = 0.26f * (1.0f + gstd);
    params[0] = 1.0f / (asig + 1e-6f);
    params[1] = 1.0f / (1.0f + expf(-(gstd - 0.1f) * 10.0f));
  }
  __syncthreads();
  for (int i = threadIdx.x; i < 1600; i += 64) accz[i] = 0.0;
}

__global__ __launch_bounds__(256) void init_embed(const float* __restrict__ xyz,
                                                  const float* __restrict__ params,
                                                  float* __restrict__ feat) {
  int t = blockIdx.x * 256 + threadIdx.x;  // over 8*4096*64
  int j = t & 63;
  int n = (t >> 6) & 4095;
  int b = t >> 18;
  float inv_ae = params[0], blend = params[1];
  int idx = (int)((double)j * 65.0 / 63.0);
  int c = idx / 22, f = idx - c * 22;
  float fv = (float)(-1.0 + 2.0 * (double)(f + 1) / 23.0);
  float v = xyz[((size_t)b * 4096 + n) * 3 + c];
  float z = (v - fv) * inv_ae;
  float e = __expf(-0.5f * z * z);
  float co = __cosf(z);
  feat[t] = blend * e + (1.0f - blend) * co;
}

// ================= fused embed + gate + K-reduce + gelu =====================
template <int C, int TWOC, int BLK, int FD>
__global__ __launch_bounds__(BLK) void fused_kernel(const float* __restrict__ x,
                                                    const float* __restrict__ xs,
                                                    const float* __restrict__ feat_in,
                                                    const int* __restrict__ fidx,
                                                    const int* __restrict__ knn,
                                                    const float* __restrict__ pstd,
                                                    float* __restrict__ feat_out, int S, int N) {
  constexpr int JPT = TWOC / BLK;
  int q = blockIdx.x;
  int b = q / S;
  int tid = threadIdx.x;
  float inv_ae = pstd[64];
  float blend = pstd[65];
  float omb = 1.0f - blend;
  float c0 = xs[(size_t)q * 3 + 0];
  float c1 = xs[(size_t)q * 3 + 1];
  float c2 = xs[(size_t)q * 3 + 2];
  const float* fsrow = feat_in + ((size_t)b * N + fidx[q]) * C;

  int cj[JPT];
  float fvj[JPT], fj[JPT], sum[JPT], mx[JPT];
#pragma unroll
  for (int i = 0; i < JPT; ++i) {
    int j = tid + i * BLK;
    int idx = (int)((double)j * (double)(3 * FD - 1) / (double)(TWOC - 1));
    int c = idx / FD, f = idx - c * FD;
    cj[i] = c;
    fvj[i] = (float)(-1.0 + 2.0 * (double)(f + 1) / (double)(FD + 1));
    fj[i] = fsrow[j < C ? j : j - C];
    sum[i] = 0.0f;
    mx[i] = -3.4e38f;
  }

  const int* krow = knn + (size_t)q * 32;
#pragma unroll 1
  for (int k = 0; k < 32; ++k) {
    int nbr = krow[k];
    float isx = pstd[k], isf = pstd[32 + k];
    const float* xr = x + ((size_t)b * N + nbr) * 3;
    float xk0 = (xr[0] - c0) * isx;
    float xk1 = (xr[1] - c1) * isx;
    float xk2 = (xr[2] - c2) * isx;
    const float* fr = feat_in + ((size_t)b * N + nbr) * C;
#pragma unroll
    for (int i = 0; i < JPT; ++i) {
      int j = tid + i * BLK;
      float cat;
      if (j < C)
        cat = (fr[j] - fj[i]) * isf;
      else
        cat = fj[i];
      float xc = (cj[i] == 0) ? xk0 : ((cj[i] == 1) ? xk1 : xk2);
      float z = (xc - fvj[i]) * inv_ae;
      float comb = blend * __expf(-0.5f * z * z) + omb * __cosf(z);
      float fw = (cat + comb) * comb;
      sum[i] += fw;
      mx[i] = fmaxf(mx[i], fw);
    }
  }
#pragma unroll
  for (int i = 0; i < JPT; ++i) {
    float val = sum[i] * 0.03125f + mx[i];
    float g = 0.5f * val * (1.0f + erff(val * 0.7071067811865476f));
    feat_out[(size_t)q * TWOC + tid + i * BLK] = g;
  }
}

// ================= stage result reduce (max & mean over S) =================
template <int TWOC, int BLK>
__global__ __launch_bounds__(BLK) void result_partial(const float* __restrict__ feat,
                                                      float* __restrict__ pmax,
                                                      double* __restrict__ psum, int S) {
  int j = blockIdx.x * BLK + threadIdx.x;
  int ch = blockIdx.y, b = blockIdx.z;
  int rows = S >> 3;
  int s0 = ch * rows;
  float m = -3.4e38f;
  double sd = 0.0;
  for (int s = 0; s < rows; ++s) {
    float v = feat[((size_t)(b * S + s0 + s)) * TWOC + j];
    m = fmaxf(m, v);
    sd += (double)v;
  }
  pmax[((size_t)ch * 8 + b) * TWOC + j] = m;
  psum[((size_t)ch * 8 + b) * TWOC + j] = sd;
}

__global__ void result_final(const float* __restrict__ pmax, const double* __restrict__ psum,
                             float* __restrict__ out, int TWOC, int off, int S) {
  int t = blockIdx.x * 256 + threadIdx.x;
  if (t >= 8 * TWOC) return;
  int b = t / TWOC, j = t - b * TWOC;
  float m = -3.4e38f;
  double sd = 0.0;
  for (int ch = 0; ch < 8; ++ch) {
    m = fmaxf(m, pmax[((size_t)ch * 8 + b) * TWOC + j]);
    sd += psum[((size_t)ch * 8 + b) * TWOC + j];
  }
  out[(size_t)b * 3840 + off + j] = m;
  out[(size_t)b * 3840 + off + TWOC + j] = (float)(sd / (double)S);
}

// ================= stage tail (stats -> fin -> fused -> result) =============
template <int N, int S, int C, int TWOC, int FD, int BLKF>
static void run_tail(const float* x, const float* xs, const float* feat_in, const int* fidx,
                     const int* knnb, double* acc, float* pstd, float* feat_out, float* pmax,
                     double* psum, float* out, int outoff, hipStream_t stream) {
  stats1_kernel<C><<<(8 * S) / 32, 256, 0, stream>>>(x, xs, feat_in, fidx, knnb, acc, S, N);
  fin_kernel<<<1, 64, 0, stream>>>(acc, pstd, S, C);
  fused_kernel<C, TWOC, BLKF, FD><<<8 * S, BLKF, 0, stream>>>(x, xs, feat_in, fidx, knnb, pstd,
                                                              feat_out, S, N);
  constexpr int RBLK = (TWOC < 256) ? TWOC : 256;
  result_partial<TWOC, RBLK><<<dim3(TWOC / RBLK, 8, 8), RBLK, 0, stream>>>(feat_out, pmax, psum, S);
  result_final<<<(8 * TWOC + 255) / 256, 256, 0, stream>>>(pmax, psum, out, TWOC, outoff, S);
}

extern "C" void kernel_launch(void* const* d_in, const int* in_sizes, int n_in, void* d_out,
                              int out_size, void* d_ws, size_t ws_size, hipStream_t stream) {
  (void)in_sizes;
  (void)n_in;
  (void)out_size;
  (void)ws_size;
  const float* xyz = (const float*)d_in[0];
  float* out = (float*)d_out;
  char* w = (char*)d_ws;

  float* featA = (float*)(w + WS_FEAT_A);
  float* featB = (float*)(w + WS_FEAT_B);
  float* xs0 = (float*)(w + WS_XS0);
  float* xs1 = (float*)(w + WS_XS1);
  float* xs2 = (float*)(w + WS_XS2);
  float* xs3 = (float*)(w + WS_XS3);
  int* fp0 = (int*)(w + WS_FP0);
  int* fp1 = (int*)(w + WS_FP1);
  int* fp2 = (int*)(w + WS_FP2);
  int* fp3 = (int*)(w + WS_FP3);
  int* knnb = (int*)(w + WS_KNN);
  float* pmax = (float*)(w + WS_PMAX);
  double* psum = (double*)(w + WS_PSUM);
  double* acc = (double*)(w + WS_ACC);
  double* acci = (double*)(w + WS_ACCI);
  float* pstd = (float*)(w + WS_PSTD);
  float* pinit = (float*)(w + WS_PINIT);

  // init embed of xyz -> featA; fin_init zeroes the stage accumulators
  // (d_ws is re-poisoned before every timed launch, so this runs every call).
  init_stats<<<24, 256, 0, stream>>>(xyz, acci);
  fin_init<<<1, 64, 0, stream>>>(acci, pinit, acc);
  init_embed<<<(8 * 4096 * 64) / 256, 256, 0, stream>>>(xyz, pinit, featA);

  // ---- stage 0 (N=4096,S=2048,C=64) ----
  fps_kernel<256, 16><<<8, 256, 0, stream>>>(xyz, fp0, xs0, 2048);
  // fps1 (needs xs0) runs concurrently with knn0 (needs xs0, xyz)
  co_fps_knn<256, 8, 64, 4><<<8 + 4096, 256, 0, stream>>>(xs0, fp1, xs1, 1024,
                                                          xyz, xs0, knnb, 2048);
  run_tail<4096, 2048, 64, 128, 43, 128>(xyz, xs0, featA, fp0, knnb, acc, pstd, featB,
                                         pmax, psum, out, 0, stream);

  // ---- stage 1 (N=2048,S=1024,C=128); fps2 single-wave ∥ knn1 ----
  co_fps_knn<64, 16, 32, 1><<<8 + 8192, 64, 0, stream>>>(xs1, fp2, xs2, 512,
                                                         xs0, xs1, knnb, 1024);
  run_tail<2048, 1024, 128, 256, 86, 256>(xs0, xs1, featB, fp1, knnb, acc, pstd, featA,
                                          pmax, psum, out, 256, stream);

  // ---- stage 2 (N=1024,S=512,C=256); fps3 single-wave ∥ knn2 ----
  co_fps_knn<64, 8, 16, 1><<<8 + 4096, 64, 0, stream>>>(xs2, fp3, xs3, 256,
                                                        xs1, xs2, knnb, 512);
  run_tail<1024, 512, 256, 512, 171, 256>(xs1, xs2, featA, fp2, knnb, acc, pstd, featB,
                                          pmax, psum, out, 768, stream);

  // ---- stage 3 (N=512,S=256,C=512) ----
  knn_kernel<8><<<512, 256, 0, stream>>>(xs2, xs3, knnb, 256);
  run_tail<512, 256, 512, 1024, 342, 256>(xs2, xs3, featB, fp3, knnb, acc, pstd, featA,
                                          pmax, psum, out, 1792, stream);
}

// Round 11
// 2472.394 us; speedup vs baseline: 1.9051x; 1.0417x over previous
//
#include <hip/hip_runtime.h>

typedef unsigned int u32;
typedef unsigned long long u64;
typedef float f32x2 __attribute__((ext_vector_type(2)));

// ---------------- workspace layout (bytes, non-overlapping) ----------------
#define WS_FEAT_A   0            // 8,388,608
#define WS_FEAT_B   8388608      // 8,388,608 -> 16,777,216
#define WS_XS0      16777216     // 196,608
#define WS_XS1      16973824     // 98,304
#define WS_XS2      17072128     // 49,152
#define WS_XS3      17121280     // 24,576
#define WS_FP0      17145856     // 65,536
#define WS_FP1      17211392     // 32,768
#define WS_FP2      17244160     // 16,384
#define WS_FP3      17260544     // 8,192
#define WS_ACC      17268736     // 1600 dbl = 12,800
#define WS_ACCI     17281536     // 384
#define WS_PSTD     17281920     // 512
#define WS_PINIT    17282432     // 128
#define WS_KN0      17282560     // 2,097,152
#define WS_KN1      19379712     // 1,048,576
#define WS_KN2      20428288     // 524,288
#define WS_KN3      20952576     // 262,144
#define WS_PMAX     21214720     // 262,144
#define WS_PSUM     21476864     // 524,288 -> ends 22,001,152

// ---- packed f32 (VOP3P) — exact IEEE mul/add on each half ----
__device__ __forceinline__ f32x2 pk_add(f32x2 a, f32x2 b) {
  f32x2 d;
  asm("v_pk_add_f32 %0, %1, %2" : "=v"(d) : "v"(a), "v"(b));
  return d;
}
__device__ __forceinline__ f32x2 pk_mul(f32x2 a, f32x2 b) {
  f32x2 d;
  asm("v_pk_mul_f32 %0, %1, %2" : "=v"(d) : "v"(a), "v"(b));
  return d;
}

// ---- DPP wave64 reductions (VALU) ----
__device__ __forceinline__ u32 dpp_umax_l63(u32 v) {
  u32 t;
  t = (u32)__builtin_amdgcn_update_dpp(0, (int)v, 0x111, 0xf, 0xf, true); v = t > v ? t : v;
  t = (u32)__builtin_amdgcn_update_dpp(0, (int)v, 0x112, 0xf, 0xf, true); v = t > v ? t : v;
  t = (u32)__builtin_amdgcn_update_dpp(0, (int)v, 0x114, 0xf, 0xf, true); v = t > v ? t : v;
  t = (u32)__builtin_amdgcn_update_dpp(0, (int)v, 0x118, 0xf, 0xf, true); v = t > v ? t : v;
  t = (u32)__builtin_amdgcn_update_dpp(0, (int)v, 0x142, 0xf, 0xf, true); v = t > v ? t : v;
  t = (u32)__builtin_amdgcn_update_dpp(0, (int)v, 0x143, 0xf, 0xf, true); v = t > v ? t : v;
  return (u32)__builtin_amdgcn_readlane((int)v, 63);
}

__device__ __forceinline__ u32 dpp_umin_l63(u32 v) {
  u32 t;
  t = (u32)__builtin_amdgcn_update_dpp(-1, (int)v, 0x111, 0xf, 0xf, false); v = t < v ? t : v;
  t = (u32)__builtin_amdgcn_update_dpp(-1, (int)v, 0x112, 0xf, 0xf, false); v = t < v ? t : v;
  t = (u32)__builtin_amdgcn_update_dpp(-1, (int)v, 0x114, 0xf, 0xf, false); v = t < v ? t : v;
  t = (u32)__builtin_amdgcn_update_dpp(-1, (int)v, 0x118, 0xf, 0xf, false); v = t < v ? t : v;
  t = (u32)__builtin_amdgcn_update_dpp(-1, (int)v, 0x142, 0xf, 0xf, false); v = t < v ? t : v;
  t = (u32)__builtin_amdgcn_update_dpp(-1, (int)v, 0x143, 0xf, 0xf, false); v = t < v ? t : v;
  return (u32)__builtin_amdgcn_readlane((int)v, 63);
}

// ---- strict (non-contracted) float math matching numpy op order ----
__device__ __forceinline__ float sumsq3_nc(float x, float y, float z) {
#pragma clang fp contract(off)
  float d = x * x;
  d = d + y * y;
  d = d + z * z;
  return d;
}

__device__ __forceinline__ float knn_dist_nc(float qx, float qy, float qz, float qsq,
                                             float nx, float ny, float nz) {
#pragma clang fp contract(off)
  float dot = qx * nx;
  dot = dot + qy * ny;
  dot = dot + qz * nz;
  float nsq = nx * nx;
  nsq = nsq + ny * ny;
  nsq = nsq + nz * nz;
  float d = -2.0f * dot;
  d = d + qsq;
  d = d + nsq;
  return d;
}

// ================= FPS body (round-6 structure, best measured) =============
// exact pointnet2 semantics (start at index 0); writes out_idx AND xs coords.
// NW==1 path has NO barrier (safe under a tid<64 guard inside wider blocks);
// wave-local LDS RAW ordering enforced by lgkmcnt(0).
template <int BLK, int P>
__device__ __forceinline__ void fps_body(const float* __restrict__ x,
                                         int* __restrict__ out_idx,
                                         float* __restrict__ xs, int S, int b) {
  constexpr int NW = BLK / 64;
  constexpr int PH = P / 2;
  const int N = BLK * P;
  const float* xb = x + (size_t)b * N * 3;
  const int tid = threadIdx.x;
  const int lane = tid & 63;
  const int wid = tid >> 6;

  __shared__ float4 spts[BLK * P];
  __shared__ alignas(16) u64 skey[2][NW < 2 ? 2 : NW];
  __shared__ int sidx[(NW > 1) ? (BLK * P / 2) : 1];

  f32x2 px2[PH], py2[PH], pz2[PH];
  float dist[P];
#pragma unroll
  for (int i = 0; i < P; ++i) {
    int idx = i * BLK + tid;
    float a = xb[idx * 3 + 0];
    float c = xb[idx * 3 + 1];
    float d = xb[idx * 3 + 2];
    px2[i >> 1][i & 1] = a;
    py2[i >> 1][i & 1] = c;
    pz2[i >> 1][i & 1] = d;
    dist[i] = 1e10f;
    spts[idx] = make_float4(a, c, d, 0.0f);
  }
  if constexpr (NW > 1) {
    __syncthreads();
  } else {
    asm volatile("s_waitcnt lgkmcnt(0)" ::: "memory");
  }

  float4 l4 = spts[0];
  float lx = l4.x, ly = l4.y, lz = l4.z;
  if constexpr (NW == 1) {
    if (tid == 0) {
      out_idx[b * S + 0] = 0;
      xs[(size_t)(b * S) * 3 + 0] = lx;
      xs[(size_t)(b * S) * 3 + 1] = ly;
      xs[(size_t)(b * S) * 3 + 2] = lz;
    }
  }

#pragma unroll 1
  for (int it = 1; it < S; ++it) {
    const int p = it & 1;
    f32x2 vnx, vny, vnz;
    vnx[0] = vnx[1] = __uint_as_float(__float_as_uint(lx) ^ 0x80000000u);
    vny[0] = vny[1] = __uint_as_float(__float_as_uint(ly) ^ 0x80000000u);
    vnz[0] = vnz[1] = __uint_as_float(__float_as_uint(lz) ^ 0x80000000u);
    u32 bd = 0;
    int bi = 0;
#pragma unroll
    for (int j = 0; j < PH; ++j) {
      f32x2 dx = pk_add(px2[j], vnx);
      f32x2 dy = pk_add(py2[j], vny);
      f32x2 dz = pk_add(pz2[j], vnz);
      f32x2 m0 = pk_mul(dx, dx);
      f32x2 m1 = pk_mul(dy, dy);
      f32x2 m2 = pk_mul(dz, dz);
      f32x2 s = pk_add(pk_add(m0, m1), m2);
#pragma unroll
      for (int h = 0; h < 2; ++h) {
        int i = 2 * j + h;
        float dm = fminf(dist[i], s[h]);
        dist[i] = dm;
        u32 db = __float_as_uint(dm);
        bool g = db > bd;  // strict > keeps smallest local idx (argmax first-occurrence)
        bd = g ? db : bd;
        bi = g ? i : bi;
      }
    }
    u32 bidx = (u32)(bi * BLK + tid);

    u32 maxb = dpp_umax_l63(bd);
    u64 cm = __ballot(bd == maxb);
    u32 widx;
    if (__popcll(cm) == 1) {
      widx = (u32)__builtin_amdgcn_readlane((int)bidx, (int)__ffsll((long long)cm) - 1);
    } else {
      widx = 0xFFFFFFFFu - dpp_umax_l63((bd == maxb) ? (0xFFFFFFFFu - bidx) : 0u);
    }

    if constexpr (NW > 1) {
      if (lane == 0) skey[p][wid] = ((u64)maxb << 32) | (u64)(0xFFFFFFFFu - widx);
      __syncthreads();
      u64 best = skey[p][0];
#pragma unroll
      for (int w = 1; w < NW; ++w) {
        u64 kk = skey[p][w];
        best = (kk > best) ? kk : best;
      }
      widx = 0xFFFFFFFFu - (u32)best;
      if (tid == 0) sidx[it] = (int)widx;
    }

    float4 c4 = spts[widx];
    lx = c4.x;
    ly = c4.y;
    lz = c4.z;

    if constexpr (NW == 1) {
      if (lane == 0) {
        out_idx[b * S + it] = (int)widx;
        xs[(size_t)(b * S + it) * 3 + 0] = lx;
        xs[(size_t)(b * S + it) * 3 + 1] = ly;
        xs[(size_t)(b * S + it) * 3 + 2] = lz;
      }
    }
  }

  if constexpr (NW > 1) {
    __syncthreads();
    for (int i = tid; i < S; i += BLK) {
      int idx = (i == 0) ? 0 : sidx[i];
      out_idx[b * S + i] = idx;
      float4 c4 = spts[idx];
      xs[(size_t)(b * S + i) * 3 + 0] = c4.x;
      xs[(size_t)(b * S + i) * 3 + 1] = c4.y;
      xs[(size_t)(b * S + i) * 3 + 2] = c4.z;
    }
  }
}

// ================= kNN body (wave per query; DPP-min rounds, exact) ========
template <int P>  // N = 64*P candidates
__device__ __forceinline__ void knn_body(const float* __restrict__ x,
                                         const float* __restrict__ xs,
                                         int* __restrict__ knn, int S, int q, int lane) {
  int b = q / S;
  const int N = 64 * P;
  const float* xb = x + (size_t)b * N * 3;
  float qx = xs[(size_t)q * 3 + 0];
  float qy = xs[(size_t)q * 3 + 1];
  float qz = xs[(size_t)q * 3 + 2];
  float qsq = sumsq3_nc(qx, qy, qz);

  u64 key[P];
#pragma unroll
  for (int i = 0; i < P; ++i) {
    int idx = i * 64 + lane;
    float nx = xb[idx * 3 + 0], ny = xb[idx * 3 + 1], nz = xb[idx * 3 + 2];
    float d = knn_dist_nc(qx, qy, qz, qsq, nx, ny, nz);
    u32 u = __float_as_uint(d);
    u32 msk = ((u32)(((int)u) >> 31)) | 0x80000000u;  // sortable float mapping
    u ^= msk;
    key[i] = ((u64)u << 32) | (u64)(u32)idx;
  }

  u64 prev = 0;
  u32 myv = 0;
#pragma unroll 1
  for (int r = 0; r < 32; ++r) {
    u64 best = ~0ull;
#pragma unroll
    for (int i = 0; i < P; ++i) {
      u64 k = key[i];
      u64 cand = (k > prev) ? k : ~0ull;
      best = (cand < best) ? cand : best;
    }
    u32 hi = (u32)(best >> 32);
    u32 minb = dpp_umin_l63(hi);
    u64 cm = __ballot(hi == minb);
    u32 lo;
    if (__popcll(cm) == 1) {
      lo = (u32)__builtin_amdgcn_readlane((int)(u32)best, (int)__ffsll((long long)cm) - 1);
    } else {
      lo = dpp_umin_l63(hi == minb ? (u32)best : 0xFFFFFFFFu);
    }
    prev = ((u64)minb << 32) | lo;
    if (lane == r) myv = lo;
  }
  if (lane < 32) knn[(size_t)q * 32 + lane] = (int)myv;
}

// ================= stats1 body: per-(b,c,k) raw sums + per-k feat sums ======
template <int C>
__device__ __forceinline__ void stats1_body(const float* __restrict__ x,
                                            const float* __restrict__ xs,
                                            const float* __restrict__ feat,
                                            const int* __restrict__ fidx,
                                            const int* __restrict__ knn,
                                            double* __restrict__ acc, int S, int N, int bid) {
  int k = threadIdx.x & 31;
  int qs = threadIdx.x >> 5;  // 0..7
  int qbase = bid * 32;
  int b = qbase / S;  // uniform per block (S multiple of 32)
  double sx[3] = {0, 0, 0}, sxx[3] = {0, 0, 0}, sf = 0, sff = 0;
  for (int jj = 0; jj < 4; ++jj) {
    int q = qbase + qs * 4 + jj;
    int nbr = knn[(size_t)q * 32 + k];
    int fq = fidx[q];
    const float* xr = x + ((size_t)b * N + nbr) * 3;
    const float* xq = xs + (size_t)q * 3;
#pragma unroll
    for (int c = 0; c < 3; ++c) {
      float d = xr[c] - xq[c];
      sx[c] += (double)d;
      sxx[c] += (double)d * (double)d;
    }
    const float4* fr = (const float4*)(feat + ((size_t)b * N + nbr) * C);
    const float4* fqv = (const float4*)(feat + ((size_t)b * N + fq) * C);
    for (int c = 0; c < C / 4; ++c) {
      float4 a = fr[c], bb = fqv[c];
      float d0 = a.x - bb.x, d1 = a.y - bb.y, d2 = a.z - bb.z, d3 = a.w - bb.w;
      sf += (double)d0 + (double)d1 + (double)d2 + (double)d3;
      sff += (double)d0 * d0 + (double)d1 * d1 + (double)d2 * d2 + (double)d3 * d3;
    }
  }
  __shared__ double red[256];
  double vals[8] = {sx[0], sxx[0], sx[1], sxx[1], sx[2], sxx[2], sf, sff};
  double* accG = acc;
  double* acc_fk = acc + 1536;
#pragma unroll
  for (int p = 0; p < 8; ++p) {
    red[threadIdx.x] = vals[p];
    __syncthreads();
    if (threadIdx.x < 32) {
      double r = 0;
#pragma unroll
      for (int t = 0; t < 8; ++t) r += red[k + t * 32];
      if (p < 6) {
        int c = p >> 1;
        atomicAdd(&accG[((b * 3 + c) * 32 + k) * 2 + (p & 1)], r);
      } else {
        atomicAdd(&acc_fk[k * 2 + (p & 1)], r);
      }
    }
    __syncthreads();
  }
}

template <int C>
__global__ __launch_bounds__(256) void stats1_kernel(const float* __restrict__ x,
                                                     const float* __restrict__ xs,
                                                     const float* __restrict__ feat,
                                                     const int* __restrict__ fidx,
                                                     const int* __restrict__ knn,
                                                     double* __restrict__ acc, int S, int N) {
  stats1_body<C>(x, xs, feat, fidx, knn, acc, S, N, blockIdx.x);
}

// ================= fused body: embed + gate + K-reduce + gelu ===============
template <int C, int TWOC, int BLK, int FD>
__device__ __forceinline__ void fused_body(const float* __restrict__ x,
                                           const float* __restrict__ xs,
                                           const float* __restrict__ feat_in,
                                           const int* __restrict__ fidx,
                                           const int* __restrict__ knn,
                                           const float* __restrict__ pstd,
                                           float* __restrict__ feat_out, int S, int N, int q) {
  constexpr int JPT = TWOC / BLK;
  int b = q / S;
  int tid = threadIdx.x;
  float inv_ae = pstd[64];
  float blend = pstd[65];
  float omb = 1.0f - blend;
  float c0 = xs[(size_t)q * 3 + 0];
  float c1 = xs[(size_t)q * 3 + 1];
  float c2 = xs[(size_t)q * 3 + 2];
  const float* fsrow = feat_in + ((size_t)b * N + fidx[q]) * C;

  int cj[JPT];
  float fvj[JPT], fj[JPT], sum[JPT], mx[JPT];
#pragma unroll
  for (int i = 0; i < JPT; ++i) {
    int j = tid + i * BLK;
    int idx = (int)((double)j * (double)(3 * FD - 1) / (double)(TWOC - 1));
    int c = idx / FD, f = idx - c * FD;
    cj[i] = c;
    fvj[i] = (float)(-1.0 + 2.0 * (double)(f + 1) / (double)(FD + 1));
    fj[i] = fsrow[j < C ? j : j - C];
    sum[i] = 0.0f;
    mx[i] = -3.4e38f;
  }

  const int* krow = knn + (size_t)q * 32;
#pragma unroll 1
  for (int k = 0; k < 32; ++k) {
    int nbr = krow[k];
    float isx = pstd[k], isf = pstd[32 + k];
    const float* xr = x + ((size_t)b * N + nbr) * 3;
    float xk0 = (xr[0] - c0) * isx;
    float xk1 = (xr[1] - c1) * isx;
    float xk2 = (xr[2] - c2) * isx;
    const float* fr = feat_in + ((size_t)b * N + nbr) * C;
#pragma unroll
    for (int i = 0; i < JPT; ++i) {
      int j = tid + i * BLK;
      float cat;
      if (j < C)
        cat = (fr[j] - fj[i]) * isf;
      else
        cat = fj[i];
      float xc = (cj[i] == 0) ? xk0 : ((cj[i] == 1) ? xk1 : xk2);
      float z = (xc - fvj[i]) * inv_ae;
      float comb = blend * __expf(-0.5f * z * z) + omb * __cosf(z);
      float fw = (cat + comb) * comb;
      sum[i] += fw;
      mx[i] = fmaxf(mx[i], fw);
    }
  }
#pragma unroll
  for (int i = 0; i < JPT; ++i) {
    float val = sum[i] * 0.03125f + mx[i];
    float g = 0.5f * val * (1.0f + erff(val * 0.7071067811865476f));
    feat_out[(size_t)q * TWOC + tid + i * BLK] = g;
  }
}

template <int C, int TWOC, int BLK, int FD>
__global__ __launch_bounds__(BLK) void fused_kernel(const float* __restrict__ x,
                                                    const float* __restrict__ xs,
                                                    const float* __restrict__ feat_in,
                                                    const int* __restrict__ fidx,
                                                    const int* __restrict__ knn,
                                                    const float* __restrict__ pstd,
                                                    float* __restrict__ feat_out, int S, int N) {
  fused_body<C, TWOC, BLK, FD>(x, xs, feat_in, fidx, knn, pstd, feat_out, S, N, blockIdx.x);
}

// ================= fin: per-stage params (once), then zero acc ==============
__global__ void fin_kernel(double* __restrict__ acc, float* __restrict__ pstd, int S, int C) {
  __shared__ float sisx[32];
  __shared__ double gslot[24];
  int tid = threadIdx.x;
  const double* accG = acc;
  const double* afk = acc + 1536;
  if (tid < 32) {
    double sd = 0, sdd = 0;
    for (int bc = 0; bc < 24; ++bc) {
      sd += accG[(bc * 32 + tid) * 2];
      sdd += accG[(bc * 32 + tid) * 2 + 1];
    }
    int n1 = 8 * S * 3;
    double var = (sdd - sd * sd / (double)n1) / (double)(n1 - 1);
    float st = fmaxf((float)sqrt(var > 0.0 ? var : 0.0), 1e-5f);
    sisx[tid] = 1.0f / st;
    pstd[tid] = sisx[tid];
    double s = afk[tid * 2], ss = afk[tid * 2 + 1];
    int n2 = 8 * S * C;
    var = (ss - s * s / (double)n2) / (double)(n2 - 1);
    st = fmaxf((float)sqrt(var > 0.0 ? var : 0.0), 1e-5f);
    pstd[32 + tid] = 1.0f / st;
  }
  __syncthreads();
  if (tid < 24) {
    double A = 0, B = 0;
    for (int k = 0; k < 32; ++k) {
      double is = (double)sisx[k];
      A += is * accG[(tid * 32 + k) * 2];
      B += is * is * accG[(tid * 32 + k) * 2 + 1];
    }
    int ng = S * 32;
    double var = (B - A * A / (double)ng) / (double)(ng - 1);
    gslot[tid] = sqrt(var > 0.0 ? var : 0.0);
  }
  __syncthreads();
  if (tid == 0) {
    double g = 0;
    for (int i = 0; i < 24; ++i) g += gslot[i];
    float gstd = (float)(g / 24.0);
    float asig = 0.26f * (1.0f + gstd);
    pstd[64] = 1.0f / (asig + 1e-6f);
    pstd[65] = 1.0f / (1.0f + expf(-(gstd - 0.1f) * 10.0f));
  }
  __syncthreads();
  for (int i = tid; i < 1600; i += 64) acc[i] = 0.0;
}

// ================= init stats + init params =================================
__global__ __launch_bounds__(256) void init_stats(const float* __restrict__ xyz,
                                                  double* __restrict__ acc) {
  int bc = blockIdx.x;
  int b = bc / 3, c = bc - b * 3;
  double s = 0, ss = 0;
  for (int n = threadIdx.x; n < 4096; n += 256) {
    float v = xyz[((size_t)b * 4096 + n) * 3 + c];
    s += (double)v;
    ss += (double)v * (double)v;
  }
  __shared__ double r1[256], r2[256];
  r1[threadIdx.x] = s;
  r2[threadIdx.x] = ss;
  __syncthreads();
  for (int off = 128; off > 0; off >>= 1) {
    if (threadIdx.x < off) {
      r1[threadIdx.x] += r1[threadIdx.x + off];
      r2[threadIdx.x] += r2[threadIdx.x + off];
    }
    __syncthreads();
  }
  if (threadIdx.x == 0) {
    acc[bc * 2] = r1[0];
    acc[bc * 2 + 1] = r2[0];
  }
}

__global__ void fin_init(const double* __restrict__ acc, float* __restrict__ params,
                         double* __restrict__ accz) {
  if (threadIdx.x == 0) {
    double g = 0;
    for (int i = 0; i < 24; ++i) {
      double s = acc[i * 2], ss = acc[i * 2 + 1];
      double var = (ss - s * s / 4096.0) / 4095.0;
      g += sqrt(var > 0.0 ? var : 0.0);
    }
    float gstd = (float)(g / 24.0);
    float asig = 0.26f * (1.0f + gstd);
    params[0] = 1.0f / (asig + 1e-6f);
    params[1] = 1.0f / (1.0f + expf(-(gstd - 0.1f) * 10.0f));
  }
  __syncthreads();
  for (int i = threadIdx.x; i < 1600; i += 64) accz[i] = 0.0;
}

__device__ __forceinline__ void init_embed_body(const float* __restrict__ xyz,
                                                const float* __restrict__ params,
                                                float* __restrict__ feat, int t) {
  int j = t & 63;
  int n = (t >> 6) & 4095;
  int b = t >> 18;
  float inv_ae = params[0], blend = params[1];
  int idx = (int)((double)j * 65.0 / 63.0);
  int c = idx / 22, f = idx - c * 22;
  float fv = (float)(-1.0 + 2.0 * (double)(f + 1) / 23.0);
  float v = xyz[((size_t)b * 4096 + n) * 3 + c];
  float z = (v - fv) * inv_ae;
  float e = __expf(-0.5f * z * z);
  float co = __cosf(z);
  feat[t] = blend * e + (1.0f - blend) * co;
}

// ================= co-kernels (dependency-packed) ===========================
// coA: blocks 0..7 fps0 (256thr); rest init_embed.
__global__ __launch_bounds__(256) void co_a_kernel(const float* __restrict__ xyz,
                                                   int* __restrict__ fp0,
                                                   float* __restrict__ xs0,
                                                   const float* __restrict__ pinit,
                                                   float* __restrict__ featA) {
  if (blockIdx.x < 8) {
    fps_body<256, 16>(xyz, fp0, xs0, 2048, blockIdx.x);
  } else {
    init_embed_body(xyz, pinit, featA, (blockIdx.x - 8) * 256 + threadIdx.x);
  }
}

// coB: blocks 0..7 fps1; rest knn0 (4 waves/block).
__global__ __launch_bounds__(256) void co_b_kernel(const float* __restrict__ xs0,
                                                   int* __restrict__ fp1,
                                                   float* __restrict__ xs1,
                                                   const float* __restrict__ xyz,
                                                   int* __restrict__ kn0) {
  if (blockIdx.x < 8) {
    fps_body<256, 8>(xs0, fp1, xs1, 1024, blockIdx.x);
  } else {
    knn_body<64>(xyz, xs0, kn0, 2048, (blockIdx.x - 8) * 4 + (threadIdx.x >> 6),
                 threadIdx.x & 63);
  }
}

// coC: blocks 0..7 fps2 (guarded 1-wave); 8..2055 knn1; 2056..2567 stats1_0.
__global__ __launch_bounds__(256) void co_c_kernel(const float* __restrict__ xs1,
                                                   int* __restrict__ fp2,
                                                   float* __restrict__ xs2,
                                                   const float* __restrict__ xs0,
                                                   int* __restrict__ kn1,
                                                   const float* __restrict__ xyz,
                                                   const float* __restrict__ featA,
                                                   const int* __restrict__ fp0,
                                                   const int* __restrict__ kn0,
                                                   double* __restrict__ acc) {
  int bid = blockIdx.x;
  if (bid < 8) {
    if (threadIdx.x < 64) fps_body<64, 16>(xs1, fp2, xs2, 512, bid);
  } else if (bid < 2056) {
    knn_body<32>(xs0, xs1, kn1, 1024, (bid - 8) * 4 + (threadIdx.x >> 6), threadIdx.x & 63);
  } else {
    stats1_body<64>(xyz, xs0, featA, fp0, kn0, acc, 2048, 4096, bid - 2056);
  }
}

// coD: blocks 0..7 fps3 (guarded); 8..2055 knn2 (2 waves/block); rest fused0.
__global__ __launch_bounds__(128) void co_d_kernel(const float* __restrict__ xs2,
                                                   int* __restrict__ fp3,
                                                   float* __restrict__ xs3,
                                                   const float* __restrict__ xs1,
                                                   int* __restrict__ kn2,
                                                   const float* __restrict__ xyz,
                                                   const float* __restrict__ xs0,
                                                   const float* __restrict__ featA,
                                                   const int* __restrict__ fp0,
                                                   const int* __restrict__ kn0,
                                                   const float* __restrict__ pstd,
                                                   float* __restrict__ featB) {
  int bid = blockIdx.x;
  if (bid < 8) {
    if (threadIdx.x < 64) fps_body<64, 8>(xs2, fp3, xs3, 256, bid);
  } else if (bid < 2056) {
    knn_body<16>(xs1, xs2, kn2, 512, (bid - 8) * 2 + (threadIdx.x >> 6), threadIdx.x & 63);
  } else {
    fused_body<64, 128, 128, 43>(xyz, xs0, featA, fp0, kn0, pstd, featB, 2048, 4096, bid - 2056);
  }
}

// coE: blocks 0..511 knn3; 512..767 stats1_1.
__global__ __launch_bounds__(256) void co_e_kernel(const float* __restrict__ xs2,
                                                   const float* __restrict__ xs3,
                                                   int* __restrict__ kn3,
                                                   const float* __restrict__ xs0,
                                                   const float* __restrict__ xs1,
                                                   const float* __restrict__ featB,
                                                   const int* __restrict__ fp1,
                                                   const int* __restrict__ kn1,
                                                   double* __restrict__ acc) {
  int bid = blockIdx.x;
  if (bid < 512) {
    knn_body<8>(xs2, xs3, kn3, 256, bid * 4 + (threadIdx.x >> 6), threadIdx.x & 63);
  } else {
    stats1_body<128>(xs0, xs1, featB, fp1, kn1, acc, 1024, 2048, bid - 512);
  }
}

// ================= stage result reduce (max & mean over S) =================
template <int TWOC, int BLK>
__global__ __launch_bounds__(BLK) void result_partial(const float* __restrict__ feat,
                                                      float* __restrict__ pmax,
                                                      double* __restrict__ psum, int S) {
  int j = blockIdx.x * BLK + threadIdx.x;
  int ch = blockIdx.y, b = blockIdx.z;
  int rows = S >> 3;
  int s0 = ch * rows;
  float m = -3.4e38f;
  double sd = 0.0;
  for (int s = 0; s < rows; ++s) {
    float v = feat[((size_t)(b * S + s0 + s)) * TWOC + j];
    m = fmaxf(m, v);
    sd += (double)v;
  }
  pmax[((size_t)ch * 8 + b) * TWOC + j] = m;
  psum[((size_t)ch * 8 + b) * TWOC + j] = sd;
}

__global__ void result_final(const float* __restrict__ pmax, const double* __restrict__ psum,
                             float* __restrict__ out, int TWOC, int off, int S) {
  int t = blockIdx.x * 256 + threadIdx.x;
  if (t >= 8 * TWOC) return;
  int b = t / TWOC, j = t - b * TWOC;
  float m = -3.4e38f;
  double sd = 0.0;
  for (int ch = 0; ch < 8; ++ch) {
    m = fmaxf(m, pmax[((size_t)ch * 8 + b) * TWOC + j]);
    sd += psum[((size_t)ch * 8 + b) * TWOC + j];
  }
  out[(size_t)b * 3840 + off + j] = m;
  out[(size_t)b * 3840 + off + TWOC + j] = (float)(sd / (double)S);
}

extern "C" void kernel_launch(void* const* d_in, const int* in_sizes, int n_in, void* d_out,
                              int out_size, void* d_ws, size_t ws_size, hipStream_t stream) {
  (void)in_sizes;
  (void)n_in;
  (void)out_size;
  (void)ws_size;
  const float* xyz = (const float*)d_in[0];
  float* out = (float*)d_out;
  char* w = (char*)d_ws;

  float* featA = (float*)(w + WS_FEAT_A);
  float* featB = (float*)(w + WS_FEAT_B);
  float* xs0 = (float*)(w + WS_XS0);
  float* xs1 = (float*)(w + WS_XS1);
  float* xs2 = (float*)(w + WS_XS2);
  float* xs3 = (float*)(w + WS_XS3);
  int* fp0 = (int*)(w + WS_FP0);
  int* fp1 = (int*)(w + WS_FP1);
  int* fp2 = (int*)(w + WS_FP2);
  int* fp3 = (int*)(w + WS_FP3);
  int* kn0 = (int*)(w + WS_KN0);
  int* kn1 = (int*)(w + WS_KN1);
  int* kn2 = (int*)(w + WS_KN2);
  int* kn3 = (int*)(w + WS_KN3);
  float* pmax = (float*)(w + WS_PMAX);
  double* psum = (double*)(w + WS_PSUM);
  double* acc = (double*)(w + WS_ACC);
  double* acci = (double*)(w + WS_ACCI);
  float* pstd = (float*)(w + WS_PSTD);
  float* pinit = (float*)(w + WS_PINIT);

  // init params (tiny) then fps0 ∥ init_embed
  init_stats<<<24, 256, 0, stream>>>(xyz, acci);
  fin_init<<<1, 64, 0, stream>>>(acci, pinit, acc);
  co_a_kernel<<<8 + 8192, 256, 0, stream>>>(xyz, fp0, xs0, pinit, featA);

  // fps1 ∥ knn0
  co_b_kernel<<<8 + 4096, 256, 0, stream>>>(xs0, fp1, xs1, xyz, kn0);

  // fps2 ∥ knn1 ∥ stats1_0
  co_c_kernel<<<2568, 256, 0, stream>>>(xs1, fp2, xs2, xs0, kn1, xyz, featA, fp0, kn0, acc);
  fin_kernel<<<1, 64, 0, stream>>>(acc, pstd, 2048, 64);

  // fused0 ∥ fps3 ∥ knn2
  co_d_kernel<<<2056 + 16384, 128, 0, stream>>>(xs2, fp3, xs3, xs1, kn2, xyz, xs0, featA, fp0,
                                                kn0, pstd, featB);
  result_partial<128, 128><<<dim3(1, 8, 8), 128, 0, stream>>>(featB, pmax, psum, 2048);
  result_final<<<(8 * 128 + 255) / 256, 256, 0, stream>>>(pmax, psum, out, 128, 0, 2048);

  // knn3 ∥ stats1_1
  co_e_kernel<<<768, 256, 0, stream>>>(xs2, xs3, kn3, xs0, xs1, featB, fp1, kn1, acc);
  fin_kernel<<<1, 64, 0, stream>>>(acc, pstd, 1024, 128);
  fused_kernel<128, 256, 256, 86><<<8192, 256, 0, stream>>>(xs0, xs1, featB, fp1, kn1, pstd,
                                                            featA, 1024, 2048);
  result_partial<256, 256><<<dim3(1, 8, 8), 256, 0, stream>>>(featA, pmax, psum, 1024);
  result_final<<<(8 * 256 + 255) / 256, 256, 0, stream>>>(pmax, psum, out, 256, 256, 1024);

  // stage 2 tail
  stats1_kernel<256><<<128, 256, 0, stream>>>(xs1, xs2, featA, fp2, kn2, acc, 512, 1024);
  fin_kernel<<<1, 64, 0, stream>>>(acc, pstd, 512, 256);
  fused_kernel<256, 512, 256, 171><<<4096, 256, 0, stream>>>(xs1, xs2, featA, fp2, kn2, pstd,
                                                             featB, 512, 1024);
  result_partial<512, 256><<<dim3(2, 8, 8), 256, 0, stream>>>(featB, pmax, psum, 512);
  result_final<<<(8 * 512 + 255) / 256, 256, 0, stream>>>(pmax, psum, out, 512, 768, 512);

  // stage 3 tail
  stats1_kernel<512><<<64, 256, 0, stream>>>(xs2, xs3, featB, fp3, kn3, acc, 256, 512);
  fin_kernel<<<1, 64, 0, stream>>>(acc, pstd, 256, 512);
  fused_kernel<512, 1024, 256, 342><<<2048, 256, 0, stream>>>(xs2, xs3, featB, fp3, kn3, pstd,
                                                              featA, 256, 512);
  result_partial<1024, 256><<<dim3(4, 8, 8), 256, 0, stream>>>(featA, pmax, psum, 256);
  result_final<<<(8 * 1024 + 255) / 256, 256, 0, stream>>>(pmax, psum, out, 1024, 1792, 256);
}